// Round 1
// baseline (704.083 us; speedup 1.0000x reference)
//
#include <hip/hip_runtime.h>

#define NB_USERS 100000
#define NB_MOVIES 20000
#define KDIM 64
#define NPTS 2000000

__device__ __forceinline__ float sigmoidf(float z) {
    return 1.0f / (1.0f + __expf(-z));
}

// Phase 1: one wave per data point. Lane k owns feature k.
// ratings[n,k] = sigmoid(r/5 * W_r[k] + b_r[k])
// x[k] = mf[m,k] * ratings[n,k]
// rbm[n,j] = sigmoid(sum_k x[k] * W_c[j,k] + b_c[j])   (lane j computes j)
// scatter-add rbm into rbu[u,:], count into nbr[u]; save rbm rows n<20000.
__global__ __launch_bounds__(256) void phase1_kernel(
    const int* __restrict__ data_users,
    const int* __restrict__ data_movies,
    const float* __restrict__ data_ratings,
    const float* __restrict__ mf,
    const float* __restrict__ W_r,
    const float* __restrict__ b_r,
    const float* __restrict__ W_c,
    const float* __restrict__ b_c,
    float* __restrict__ rbu,
    float* __restrict__ nbr,
    float* __restrict__ rbm_saved)
{
    const int lane  = threadIdx.x & 63;
    const int wave  = blockIdx.x * (blockDim.x >> 6) + (threadIdx.x >> 6);
    const int nwav  = gridDim.x * (blockDim.x >> 6);

    // per-lane parameters (row j of W_c lives in 64 VGPRs)
    const float wr = W_r[lane];
    const float br = b_r[lane];
    const float bc = b_c[lane];
    float w[KDIM];
    #pragma unroll
    for (int i = 0; i < KDIM / 4; ++i) {
        const float4 v = *reinterpret_cast<const float4*>(&W_c[lane * KDIM + i * 4]);
        w[i * 4 + 0] = v.x; w[i * 4 + 1] = v.y; w[i * 4 + 2] = v.z; w[i * 4 + 3] = v.w;
    }

    for (int n = wave; n < NPTS; n += nwav) {
        const int   u = data_users[n];
        const int   m = data_movies[n];
        const float r = data_ratings[n];

        const float rating = sigmoidf(fmaf(r * 0.2f, wr, br));
        const float x = mf[m * KDIM + lane] * rating;

        float acc = bc;
        #pragma unroll
        for (int k = 0; k < KDIM; ++k) {
            const float xk = __int_as_float(
                __builtin_amdgcn_readlane(__float_as_int(x), k));
            acc = fmaf(xk, w[k], acc);
        }
        const float rbm = sigmoidf(acc);

        atomicAdd(&rbu[(size_t)u * KDIM + lane], rbm);
        if (lane == 0) atomicAdd(&nbr[u], 1.0f);
        if (n < NB_MOVIES) rbm_saved[n * KDIM + lane] = rbm;
    }
}

// Phase 2: one wave per query i.
// uf = (rbu[u,:] - rbm_saved[x_movies[i],:]) / max(1, nbr[u]-1)
// out[i] = (mean_k(mf[xm,k]*uf[k]) * w_out + b_out) * 5
__global__ __launch_bounds__(256) void phase2_kernel(
    const int* __restrict__ x_users,
    const int* __restrict__ x_movies,
    const float* __restrict__ mf,
    const float* __restrict__ rbu,
    const float* __restrict__ nbr,
    const float* __restrict__ rbm_saved,
    const float* __restrict__ w_out,
    const float* __restrict__ b_out,
    float* __restrict__ out)
{
    const int lane = threadIdx.x & 63;
    const int wave = blockIdx.x * (blockDim.x >> 6) + (threadIdx.x >> 6);
    if (wave >= NB_USERS) return;

    const int u  = x_users[wave];
    const int xm = x_movies[wave];

    const float nb = fmaxf(1.0f, nbr[u] - 1.0f);
    const float uf = (rbu[(size_t)u * KDIM + lane] -
                      rbm_saved[xm * KDIM + lane]) / nb;
    float p = mf[xm * KDIM + lane] * uf;

    #pragma unroll
    for (int off = 32; off > 0; off >>= 1)
        p += __shfl_xor(p, off, 64);

    if (lane == 0) {
        out[wave] = (p * (1.0f / 64.0f) * w_out[0] + b_out[0]) * 5.0f;
    }
}

extern "C" void kernel_launch(void* const* d_in, const int* in_sizes, int n_in,
                              void* d_out, int out_size, void* d_ws, size_t ws_size,
                              hipStream_t stream) {
    const int*   x_users      = (const int*)  d_in[0];
    const int*   x_movies     = (const int*)  d_in[1];
    const int*   data_users   = (const int*)  d_in[2];
    const int*   data_movies  = (const int*)  d_in[3];
    const float* data_ratings = (const float*)d_in[4];
    const float* mf           = (const float*)d_in[5];
    const float* W_r          = (const float*)d_in[6];
    const float* b_r          = (const float*)d_in[7];
    const float* W_c          = (const float*)d_in[8];
    const float* b_c          = (const float*)d_in[9];
    const float* w_out        = (const float*)d_in[10];
    const float* b_out        = (const float*)d_in[11];
    float* out = (float*)d_out;

    // workspace layout (all f32):
    //   rbu       : NB_USERS * KDIM      (25.6 MB) -- must be zeroed
    //   nbr       : NB_USERS             (0.4 MB)  -- must be zeroed
    //   rbm_saved : NB_MOVIES * KDIM     (5.1 MB)  -- fully overwritten
    float* rbu       = (float*)d_ws;
    float* nbr       = rbu + (size_t)NB_USERS * KDIM;
    float* rbm_saved = nbr + NB_USERS;

    hipMemsetAsync(rbu, 0,
                   ((size_t)NB_USERS * KDIM + NB_USERS) * sizeof(float),
                   stream);

    phase1_kernel<<<2048, 256, 0, stream>>>(
        data_users, data_movies, data_ratings, mf,
        W_r, b_r, W_c, b_c, rbu, nbr, rbm_saved);

    const int waves_needed = NB_USERS;                 // one wave per query
    const int blocks2 = (waves_needed * 64 + 255) / 256;
    phase2_kernel<<<blocks2, 256, 0, stream>>>(
        x_users, x_movies, mf, rbu, nbr, rbm_saved, w_out, b_out, out);
}

// Round 2
// 544.155 us; speedup vs baseline: 1.2939x; 1.2939x over previous
//
#include <hip/hip_runtime.h>

#define NB_USERS 100000
#define NB_MOVIES 20000
#define KDIM 64
#define NPTS 2000000

typedef __bf16 bf16x8 __attribute__((ext_vector_type(8)));
typedef float  f32x4  __attribute__((ext_vector_type(4)));

__device__ __forceinline__ float sigmoidf(float z) {
    return 1.0f / (1.0f + __expf(-z));
}

// Phase 1, MFMA version.
// Each wave processes 64 data points per macro-iteration:
//   X[p,k] = mf[m_p,k] * sigmoid(r_p/5 * W_r[k] + b_r[k])   (staged to LDS, bf16)
//   rbm[p,:] = sigmoid(X @ W_c^T + b_c)                      (8x mfma 16x16x32 per 16 pts)
//   atomicAdd into rbu[u_p,:], nbr[u_p]; save rbm rows p<20000.
//
// LDS X tile: per-wave [64 pts][64 feats] bf16 (8 KB), byte addr =
//   p*128 + ((2k) ^ ((p&7)<<4))  -- XOR swizzle makes both the 2B/lane writes
//   and the ds_read_b128 A-fragment reads bank-conflict-free (<=2-way).
// A-frag (mt, kt): lane l reads 16B at row p = mt*16+(l&15), col byte
//   (kt*64 + (l>>4)*16) ^ swz  ->  k = kt*32 + (l>>4)*8 + e. B-frag uses the
//   same (l,e)->k form, so any consistent k-bijection cancels inside MFMA.
__global__ __launch_bounds__(256) void phase1_kernel(
    const int* __restrict__ data_users,
    const int* __restrict__ data_movies,
    const float* __restrict__ data_ratings,
    const float* __restrict__ mf,
    const float* __restrict__ W_r,
    const float* __restrict__ b_r,
    const float* __restrict__ W_c,
    const float* __restrict__ b_c,
    float* __restrict__ rbu,
    float* __restrict__ nbr,
    float* __restrict__ rbm_saved)
{
    __shared__ char smem[4 * 8192];
    const int lane = threadIdx.x & 63;
    const int wid  = threadIdx.x >> 6;
    char* wtile = smem + wid * 8192;

    const int wave  = blockIdx.x * (blockDim.x >> 6) + wid;
    const int nwav  = gridDim.x * (blockDim.x >> 6);

    // per-lane rating-embedding params (lane = feature k)
    const float wr = W_r[lane] * 0.2f;   // fold /MAX_RATING
    const float br = b_r[lane];

    // B fragments: all of W_c^T, bf16, loaded once.
    // bfrag[nt][kt] lane l elem e = W_c[nt*16 + (l&15)][kt*32 + (l>>4)*8 + e]
    bf16x8 bfrag[4][2];
    #pragma unroll
    for (int nt = 0; nt < 4; ++nt) {
        #pragma unroll
        for (int kt = 0; kt < 2; ++kt) {
            const float* wrow =
                &W_c[(nt * 16 + (lane & 15)) * KDIM + kt * 32 + (lane >> 4) * 8];
            #pragma unroll
            for (int e = 0; e < 8; ++e)
                bfrag[nt][kt][e] = (__bf16)wrow[e];
        }
    }
    // bias per nt (feature n = nt*16 + (lane&15))
    float bcv[4];
    #pragma unroll
    for (int nt = 0; nt < 4; ++nt) bcv[nt] = b_c[nt * 16 + (lane & 15)];

    const int niter = NPTS / 64;
    for (int it = wave; it < niter; it += nwav) {
        const int base = it * 64;
        const int   uvec = data_users[base + lane];
        const int   mvec = data_movies[base + lane];
        const float rvec = data_ratings[base + lane];

        atomicAdd(&nbr[uvec], 1.0f);

        // ---- stage X tile to LDS (lane = feature, loop over points) ----
        #pragma unroll 1
        for (int pp0 = 0; pp0 < 64; pp0 += 16) {
            float mfv[16];
            #pragma unroll
            for (int q = 0; q < 16; ++q) {
                const int m = __builtin_amdgcn_readlane(mvec, pp0 + q);
                mfv[q] = mf[(size_t)m * KDIM + lane];
            }
            #pragma unroll
            for (int q = 0; q < 16; ++q) {
                const int p = pp0 + q;
                const float r = __int_as_float(
                    __builtin_amdgcn_readlane(__float_as_int(rvec), p));
                const float remb = sigmoidf(fmaf(r, wr, br));
                const float x = mfv[q] * remb;
                const int byte = p * 128 + ((lane * 2) ^ ((p & 7) << 4));
                *(__bf16*)(wtile + byte) = (__bf16)x;
            }
        }

        // ---- MFMA + epilogue, 16 points per m-tile ----
        #pragma unroll 1
        for (int mt = 0; mt < 4; ++mt) {
            const int prow = mt * 16 + (lane & 15);
            const int swz  = (prow & 7) << 4;
            const int cb0  = ((lane >> 4) * 16) ^ swz;
            const bf16x8 a0 = *(const bf16x8*)(wtile + prow * 128 + cb0);
            const bf16x8 a1 = *(const bf16x8*)(wtile + prow * 128 + (cb0 ^ 64));

            f32x4 acc[4];
            #pragma unroll
            for (int nt = 0; nt < 4; ++nt) {
                acc[nt] = (f32x4){0.f, 0.f, 0.f, 0.f};
                acc[nt] = __builtin_amdgcn_mfma_f32_16x16x32_bf16(
                    a0, bfrag[nt][0], acc[nt], 0, 0, 0);
                acc[nt] = __builtin_amdgcn_mfma_f32_16x16x32_bf16(
                    a1, bfrag[nt][1], acc[nt], 0, 0, 0);
            }

            // D[m][n]: n = lane&15, m = (lane>>4)*4 + reg  (m89-verified)
            #pragma unroll
            for (int reg = 0; reg < 4; ++reg) {
                const int pl = mt * 16 + (lane >> 4) * 4 + reg;
                const int u  = __shfl(uvec, pl, 64);
                const int pg = base + pl;
                #pragma unroll
                for (int nt = 0; nt < 4; ++nt) {
                    const float rbm = sigmoidf(acc[nt][reg] + bcv[nt]);
                    const int   n   = nt * 16 + (lane & 15);
                    atomicAdd(&rbu[(size_t)u * KDIM + n], rbm);
                    if (pg < NB_MOVIES)
                        rbm_saved[(size_t)pg * KDIM + n] = rbm;
                }
            }
        }
    }
}

// Phase 2: one wave per query i.
__global__ __launch_bounds__(256) void phase2_kernel(
    const int* __restrict__ x_users,
    const int* __restrict__ x_movies,
    const float* __restrict__ mf,
    const float* __restrict__ rbu,
    const float* __restrict__ nbr,
    const float* __restrict__ rbm_saved,
    const float* __restrict__ w_out,
    const float* __restrict__ b_out,
    float* __restrict__ out)
{
    const int lane = threadIdx.x & 63;
    const int wave = blockIdx.x * (blockDim.x >> 6) + (threadIdx.x >> 6);
    if (wave >= NB_USERS) return;

    const int u  = x_users[wave];
    const int xm = x_movies[wave];

    const float nb = fmaxf(1.0f, nbr[u] - 1.0f);
    const float uf = (rbu[(size_t)u * KDIM + lane] -
                      rbm_saved[(size_t)xm * KDIM + lane]) / nb;
    float p = mf[(size_t)xm * KDIM + lane] * uf;

    #pragma unroll
    for (int off = 32; off > 0; off >>= 1)
        p += __shfl_xor(p, off, 64);

    if (lane == 0) {
        out[wave] = (p * (1.0f / 64.0f) * w_out[0] + b_out[0]) * 5.0f;
    }
}

extern "C" void kernel_launch(void* const* d_in, const int* in_sizes, int n_in,
                              void* d_out, int out_size, void* d_ws, size_t ws_size,
                              hipStream_t stream) {
    const int*   x_users      = (const int*)  d_in[0];
    const int*   x_movies     = (const int*)  d_in[1];
    const int*   data_users   = (const int*)  d_in[2];
    const int*   data_movies  = (const int*)  d_in[3];
    const float* data_ratings = (const float*)d_in[4];
    const float* mf           = (const float*)d_in[5];
    const float* W_r          = (const float*)d_in[6];
    const float* b_r          = (const float*)d_in[7];
    const float* W_c          = (const float*)d_in[8];
    const float* b_c          = (const float*)d_in[9];
    const float* w_out        = (const float*)d_in[10];
    const float* b_out        = (const float*)d_in[11];
    float* out = (float*)d_out;

    // workspace layout (all f32):
    //   rbu       : NB_USERS * KDIM      (25.6 MB) -- zeroed here
    //   nbr       : NB_USERS             (0.4 MB)  -- zeroed here
    //   rbm_saved : NB_MOVIES * KDIM     (5.1 MB)  -- fully overwritten
    float* rbu       = (float*)d_ws;
    float* nbr       = rbu + (size_t)NB_USERS * KDIM;
    float* rbm_saved = nbr + NB_USERS;

    hipMemsetAsync(rbu, 0,
                   ((size_t)NB_USERS * KDIM + NB_USERS) * sizeof(float),
                   stream);

    phase1_kernel<<<1024, 256, 0, stream>>>(
        data_users, data_movies, data_ratings, mf,
        W_r, b_r, W_c, b_c, rbu, nbr, rbm_saved);

    const int blocks2 = (NB_USERS * 64 + 255) / 256;
    phase2_kernel<<<blocks2, 256, 0, stream>>>(
        x_users, x_movies, mf, rbu, nbr, rbm_saved, w_out, b_out, out);
}

// Round 3
// 465.721 us; speedup vs baseline: 1.5118x; 1.1684x over previous
//
#include <hip/hip_runtime.h>

#define NB_USERS 100000
#define NB_MOVIES 20000
#define KDIM 64
#define NPTS 2000000
#define NTILES (NPTS / 64)

typedef __bf16 bf16x8 __attribute__((ext_vector_type(8)));
typedef float  f32x4  __attribute__((ext_vector_type(4)));

__device__ __forceinline__ float sigmoidf(float z) {
    return 1.0f / (1.0f + __expf(-z));
}

// ---------------- counting sort by user ----------------

__global__ __launch_bounds__(256) void hist_kernel(
    const int* __restrict__ du, int* __restrict__ hist)
{
    int i = blockIdx.x * 256 + threadIdx.x;
    const int stride = gridDim.x * 256;
    for (; i < NPTS; i += stride) atomicAdd(&hist[du[i]], 1);
}

__global__ __launch_bounds__(1024) void scan1_kernel(
    const int* __restrict__ hist, int* __restrict__ starts, int* __restrict__ bsum)
{
    __shared__ int sd[1024];
    const int t = threadIdx.x;
    const int gid = blockIdx.x * 1024 + t;
    const int val = (gid < NB_USERS) ? hist[gid] : 0;
    sd[t] = val;
    __syncthreads();
    for (int off = 1; off < 1024; off <<= 1) {
        const int x = (t >= off) ? sd[t - off] : 0;
        __syncthreads();
        sd[t] += x;
        __syncthreads();
    }
    if (gid < NB_USERS) starts[gid] = sd[t] - val;   // exclusive within block
    if (t == 1023) bsum[blockIdx.x] = sd[t];         // block total
}

__global__ void scan2_kernel(int* bsum, int nb)
{
    if (blockIdx.x == 0 && threadIdx.x == 0) {
        int run = 0;
        for (int i = 0; i < nb; ++i) { const int v = bsum[i]; bsum[i] = run; run += v; }
    }
}

__global__ __launch_bounds__(256) void scan3_kernel(
    const int* __restrict__ hist, int* __restrict__ starts,
    const int* __restrict__ bsum, int* __restrict__ cursor,
    float* __restrict__ nbrf)
{
    const int gid = blockIdx.x * 256 + threadIdx.x;
    if (gid >= NB_USERS) return;
    const int s = starts[gid] + bsum[gid >> 10];
    starts[gid] = s;
    cursor[gid] = s;
    nbrf[gid]   = (float)hist[gid];
}

__global__ __launch_bounds__(256) void scatter_kernel(
    const int* __restrict__ du, const int* __restrict__ dm,
    const float* __restrict__ dr, int* __restrict__ cursor,
    unsigned* __restrict__ sorted_um, float* __restrict__ sorted_r)
{
    int i = blockIdx.x * 256 + threadIdx.x;
    const int stride = gridDim.x * 256;
    for (; i < NPTS; i += stride) {
        const int u = du[i];
        const int pos = atomicAdd(&cursor[u], 1);
        sorted_um[pos] = ((unsigned)u << 15) | (unsigned)dm[i];
        sorted_r[pos]  = dr[i];
    }
}

// ---------------- rbm_saved: recompute rows n < 20000 from unsorted stream ----------------
// (reference quirk: rbm indexed by movie id as a data-row index)

__global__ __launch_bounds__(256) void rbm_saved_kernel(
    const int* __restrict__ dm, const float* __restrict__ dr,
    const float* __restrict__ mf,
    const float* __restrict__ W_r, const float* __restrict__ b_r,
    const float* __restrict__ W_c, const float* __restrict__ b_c,
    float* __restrict__ rbm_saved)
{
    __shared__ char smem[4 * 8192];
    const int lane = threadIdx.x & 63;
    const int wid  = threadIdx.x >> 6;
    char* wtile = smem + wid * 8192;

    const int wave = blockIdx.x * (blockDim.x >> 6) + wid;
    const int NT = (NB_MOVIES + 63) / 64;     // 313 tiles
    if (wave >= NT) return;

    const float wr = W_r[lane] * 0.2f;
    const float br = b_r[lane];

    bf16x8 bfrag[4][2];
    #pragma unroll
    for (int nt = 0; nt < 4; ++nt)
        #pragma unroll
        for (int kt = 0; kt < 2; ++kt) {
            const float* wrow =
                &W_c[(nt * 16 + (lane & 15)) * KDIM + kt * 32 + (lane >> 4) * 8];
            #pragma unroll
            for (int e = 0; e < 8; ++e) bfrag[nt][kt][e] = (__bf16)wrow[e];
        }
    float bcv[4];
    #pragma unroll
    for (int nt = 0; nt < 4; ++nt) bcv[nt] = b_c[nt * 16 + (lane & 15)];

    const int base = wave * 64;
    const int   mvec = dm[base + lane];
    const float rvec = dr[base + lane];

    #pragma unroll 1
    for (int pp0 = 0; pp0 < 64; pp0 += 16) {
        float mfv[16];
        #pragma unroll
        for (int q = 0; q < 16; ++q) {
            const int m = __builtin_amdgcn_readlane(mvec, pp0 + q);
            mfv[q] = mf[(size_t)m * KDIM + lane];
        }
        #pragma unroll
        for (int q = 0; q < 16; ++q) {
            const int p = pp0 + q;
            const float r = __int_as_float(
                __builtin_amdgcn_readlane(__float_as_int(rvec), p));
            const float x = mfv[q] * sigmoidf(fmaf(r, wr, br));
            const int byte = p * 128 + ((lane * 2) ^ ((p & 7) << 4));
            *(__bf16*)(wtile + byte) = (__bf16)x;
        }
    }

    #pragma unroll 1
    for (int mt = 0; mt < 4; ++mt) {
        const int prow = mt * 16 + (lane & 15);
        const int swz  = (prow & 7) << 4;
        const int cb0  = ((lane >> 4) * 16) ^ swz;
        const bf16x8 a0 = *(const bf16x8*)(wtile + prow * 128 + cb0);
        const bf16x8 a1 = *(const bf16x8*)(wtile + prow * 128 + (cb0 ^ 64));

        f32x4 acc[4];
        #pragma unroll
        for (int nt = 0; nt < 4; ++nt) {
            acc[nt] = (f32x4){0.f, 0.f, 0.f, 0.f};
            acc[nt] = __builtin_amdgcn_mfma_f32_16x16x32_bf16(a0, bfrag[nt][0], acc[nt], 0, 0, 0);
            acc[nt] = __builtin_amdgcn_mfma_f32_16x16x32_bf16(a1, bfrag[nt][1], acc[nt], 0, 0, 0);
        }

        #pragma unroll
        for (int reg = 0; reg < 4; ++reg) {
            const int pg = base + mt * 16 + (lane >> 4) * 4 + reg;
            if (pg < NB_MOVIES) {
                #pragma unroll
                for (int nt = 0; nt < 4; ++nt) {
                    const float rbm = sigmoidf(acc[nt][reg] + bcv[nt]);
                    rbm_saved[(size_t)pg * KDIM + nt * 16 + (lane & 15)] = rbm;
                }
            }
        }
    }
}

// ---------------- phase 1 over user-sorted points, segmented-reduce epilogue ----------------

__global__ __launch_bounds__(256) void phase1_sorted_kernel(
    const unsigned* __restrict__ sorted_um,
    const float* __restrict__ sorted_r,
    const float* __restrict__ mf,
    const float* __restrict__ W_r, const float* __restrict__ b_r,
    const float* __restrict__ W_c, const float* __restrict__ b_c,
    float* __restrict__ rbu)
{
    __shared__ char smem[4 * 8192];
    const int lane = threadIdx.x & 63;
    const int wid  = threadIdx.x >> 6;
    char* wtile = smem + wid * 8192;

    const int wave = blockIdx.x * (blockDim.x >> 6) + wid;
    const int nwav = gridDim.x * (blockDim.x >> 6);

    const float wr = W_r[lane] * 0.2f;
    const float br = b_r[lane];

    bf16x8 bfrag[4][2];
    #pragma unroll
    for (int nt = 0; nt < 4; ++nt)
        #pragma unroll
        for (int kt = 0; kt < 2; ++kt) {
            const float* wrow =
                &W_c[(nt * 16 + (lane & 15)) * KDIM + kt * 32 + (lane >> 4) * 8];
            #pragma unroll
            for (int e = 0; e < 8; ++e) bfrag[nt][kt][e] = (__bf16)wrow[e];
        }
    float bcv[4];
    #pragma unroll
    for (int nt = 0; nt < 4; ++nt) bcv[nt] = b_c[nt * 16 + (lane & 15)];

    for (int it = wave; it < NTILES; it += nwav) {
        const int base = it * 64;
        const unsigned um = sorted_um[base + lane];
        const float  rvec = sorted_r[base + lane];
        const unsigned uvec = um >> 15;
        const int      mvec = (int)(um & 0x7fffu);

        // ---- stage X tile (bf16, XOR-swizzled) ----
        #pragma unroll 1
        for (int pp0 = 0; pp0 < 64; pp0 += 16) {
            float mfv[16];
            #pragma unroll
            for (int q = 0; q < 16; ++q) {
                const int m = __builtin_amdgcn_readlane(mvec, pp0 + q);
                mfv[q] = mf[(size_t)m * KDIM + lane];
            }
            #pragma unroll
            for (int q = 0; q < 16; ++q) {
                const int p = pp0 + q;
                const float r = __int_as_float(
                    __builtin_amdgcn_readlane(__float_as_int(rvec), p));
                const float x = mfv[q] * sigmoidf(fmaf(r, wr, br));
                const int byte = p * 128 + ((lane * 2) ^ ((p & 7) << 4));
                *(__bf16*)(wtile + byte) = (__bf16)x;
            }
        }

        // ---- per-mt MFMA + segmented reduce ----
        #pragma unroll 1
        for (int mt = 0; mt < 4; ++mt) {
            const int prow = mt * 16 + (lane & 15);
            const int swz  = (prow & 7) << 4;
            const int cb0  = ((lane >> 4) * 16) ^ swz;
            const bf16x8 a0 = *(const bf16x8*)(wtile + prow * 128 + cb0);
            const bf16x8 a1 = *(const bf16x8*)(wtile + prow * 128 + (cb0 ^ 64));

            f32x4 acc[4];
            #pragma unroll
            for (int nt = 0; nt < 4; ++nt) {
                acc[nt] = (f32x4){0.f, 0.f, 0.f, 0.f};
                acc[nt] = __builtin_amdgcn_mfma_f32_16x16x32_bf16(a0, bfrag[nt][0], acc[nt], 0, 0, 0);
                acc[nt] = __builtin_amdgcn_mfma_f32_16x16x32_bf16(a1, bfrag[nt][1], acc[nt], 0, 0, 0);
            }

            // rbm[nt][reg]: point p_local = (lane>>4)*4 + reg, feature nt*16+(lane&15)
            float rbm[4][4];
            #pragma unroll
            for (int nt = 0; nt < 4; ++nt)
                #pragma unroll
                for (int reg = 0; reg < 4; ++reg)
                    rbm[nt][reg] = sigmoidf(acc[nt][reg] + bcv[nt]);

            // lanes 0..15 mirror users of points mt*16 .. mt*16+15
            const int ip = mt * 16 + (lane & 15);
            const unsigned u_at   = __shfl(uvec, ip, 64);
            const unsigned u_prev = __shfl(uvec, (ip > 0) ? ip - 1 : 0, 64);
            const bool boundary = ((lane & 15) == 0) || (u_at != u_prev);
            unsigned long long bm = __ballot(boundary) & 0xFFFFull;

            const int g = lane >> 4;
            while (bm) {
                const int s = __builtin_ctzll(bm);
                bm &= bm - 1;
                const int e = bm ? __builtin_ctzll(bm) : 16;
                const unsigned useg =
                    (unsigned)__builtin_amdgcn_readlane((int)u_at, s);

                const int lo = s - g * 4;
                const int hi = e - g * 4;
                float p0 = 0.f, p1 = 0.f, p2 = 0.f, p3 = 0.f;
                #pragma unroll
                for (int reg = 0; reg < 4; ++reg) {
                    const bool in = (reg >= lo) && (reg < hi);
                    p0 += in ? rbm[0][reg] : 0.f;
                    p1 += in ? rbm[1][reg] : 0.f;
                    p2 += in ? rbm[2][reg] : 0.f;
                    p3 += in ? rbm[3][reg] : 0.f;
                }
                p0 += __shfl_xor(p0, 16, 64); p0 += __shfl_xor(p0, 32, 64);
                p1 += __shfl_xor(p1, 16, 64); p1 += __shfl_xor(p1, 32, 64);
                p2 += __shfl_xor(p2, 16, 64); p2 += __shfl_xor(p2, 32, 64);
                p3 += __shfl_xor(p3, 16, 64); p3 += __shfl_xor(p3, 32, 64);

                const float v01 = (g & 1) ? p1 : p0;
                const float v23 = (g & 1) ? p3 : p2;
                const float val = (g & 2) ? v23 : v01;
                // one 256B-contiguous atomic: full user row
                atomicAdd(&rbu[(size_t)useg * KDIM + lane], val);
            }
        }
    }
}

// ---------------- phase 2 ----------------

__global__ __launch_bounds__(256) void phase2_kernel(
    const int* __restrict__ x_users,
    const int* __restrict__ x_movies,
    const float* __restrict__ mf,
    const float* __restrict__ rbu,
    const float* __restrict__ nbrf,
    const float* __restrict__ rbm_saved,
    const float* __restrict__ w_out,
    const float* __restrict__ b_out,
    float* __restrict__ out)
{
    const int lane = threadIdx.x & 63;
    const int wave = blockIdx.x * (blockDim.x >> 6) + (threadIdx.x >> 6);
    if (wave >= NB_USERS) return;

    const int u  = x_users[wave];
    const int xm = x_movies[wave];

    const float nb = fmaxf(1.0f, nbrf[u] - 1.0f);
    const float uf = (rbu[(size_t)u * KDIM + lane] -
                      rbm_saved[(size_t)xm * KDIM + lane]) / nb;
    float p = mf[(size_t)xm * KDIM + lane] * uf;

    #pragma unroll
    for (int off = 32; off > 0; off >>= 1)
        p += __shfl_xor(p, off, 64);

    if (lane == 0)
        out[wave] = (p * (1.0f / 64.0f) * w_out[0] + b_out[0]) * 5.0f;
}

extern "C" void kernel_launch(void* const* d_in, const int* in_sizes, int n_in,
                              void* d_out, int out_size, void* d_ws, size_t ws_size,
                              hipStream_t stream) {
    const int*   x_users      = (const int*)  d_in[0];
    const int*   x_movies     = (const int*)  d_in[1];
    const int*   data_users   = (const int*)  d_in[2];
    const int*   data_movies  = (const int*)  d_in[3];
    const float* data_ratings = (const float*)d_in[4];
    const float* mf           = (const float*)d_in[5];
    const float* W_r          = (const float*)d_in[6];
    const float* b_r          = (const float*)d_in[7];
    const float* W_c          = (const float*)d_in[8];
    const float* b_c          = (const float*)d_in[9];
    const float* w_out        = (const float*)d_in[10];
    const float* b_out        = (const float*)d_in[11];
    float* out = (float*)d_out;

    // workspace layout (~48.4 MB)
    float*    rbu       = (float*)d_ws;                       // 6.4M f32
    float*    nbrf      = rbu + (size_t)NB_USERS * KDIM;      // 100K f32
    float*    rbm_saved = nbrf + NB_USERS;                    // 1.28M f32
    int*      hist      = (int*)(rbm_saved + (size_t)NB_MOVIES * KDIM);
    int*      starts    = hist + NB_USERS;
    int*      cursor    = starts + NB_USERS;
    int*      bsum      = cursor + NB_USERS;                  // 128 ints
    unsigned* sorted_um = (unsigned*)(bsum + 128);            // 2M u32
    float*    sorted_r  = (float*)(sorted_um + NPTS);         // 2M f32

    hipMemsetAsync(rbu, 0, (size_t)NB_USERS * KDIM * sizeof(float), stream);
    hipMemsetAsync(hist, 0, NB_USERS * sizeof(int), stream);

    hist_kernel<<<2048, 256, 0, stream>>>(data_users, hist);

    const int nblk_scan = (NB_USERS + 1023) / 1024;           // 98
    scan1_kernel<<<nblk_scan, 1024, 0, stream>>>(hist, starts, bsum);
    scan2_kernel<<<1, 64, 0, stream>>>(bsum, nblk_scan);
    scan3_kernel<<<(NB_USERS + 255) / 256, 256, 0, stream>>>(hist, starts, bsum, cursor, nbrf);

    scatter_kernel<<<2048, 256, 0, stream>>>(
        data_users, data_movies, data_ratings, cursor, sorted_um, sorted_r);

    rbm_saved_kernel<<<79, 256, 0, stream>>>(
        data_movies, data_ratings, mf, W_r, b_r, W_c, b_c, rbm_saved);

    phase1_sorted_kernel<<<1024, 256, 0, stream>>>(
        sorted_um, sorted_r, mf, W_r, b_r, W_c, b_c, rbu);

    phase2_kernel<<<(NB_USERS * 64 + 255) / 256, 256, 0, stream>>>(
        x_users, x_movies, mf, rbu, nbrf, rbm_saved, w_out, b_out, out);
}

// Round 4
// 420.536 us; speedup vs baseline: 1.6743x; 1.1074x over previous
//
#include <hip/hip_runtime.h>

#define NB_USERS 100000
#define NB_MOVIES 20000
#define KDIM 64
#define NPTS 2000000
#define NTILES (NPTS / 64)
#define RQ_LEVELS 8192            // rating quantization; table rows = RQ_LEVELS+1

typedef __bf16 bf16x8 __attribute__((ext_vector_type(8)));
typedef float  f32x4  __attribute__((ext_vector_type(4)));

__device__ __forceinline__ float sigmoidf(float z) {
    return 1.0f / (1.0f + __expf(-z));
}

// ---------------- rating-embedding table ----------------
// rtab[q][k] = sigmoid((q/8192)*W_r[k] + b_r[k]),  q = round(r/5 * 8192)
__global__ __launch_bounds__(256) void rtab_kernel(
    const float* __restrict__ W_r, const float* __restrict__ b_r,
    float* __restrict__ rtab)
{
    const int idx = blockIdx.x * 256 + threadIdx.x;
    const int total = (RQ_LEVELS + 1) * KDIM;
    if (idx >= total) return;
    const int q = idx >> 6, k = idx & 63;
    rtab[idx] = sigmoidf(fmaf((float)q * (1.0f / RQ_LEVELS), W_r[k], b_r[k]));
}

// ---------------- counting sort by user ----------------

__global__ __launch_bounds__(256) void hist_kernel(
    const int* __restrict__ du, int* __restrict__ hist)
{
    int i = blockIdx.x * 256 + threadIdx.x;
    const int stride = gridDim.x * 256;
    for (; i < NPTS; i += stride) atomicAdd(&hist[du[i]], 1);
}

__global__ __launch_bounds__(1024) void scan1_kernel(
    const int* __restrict__ hist, int* __restrict__ starts, int* __restrict__ bsum)
{
    __shared__ int sd[1024];
    const int t = threadIdx.x;
    const int gid = blockIdx.x * 1024 + t;
    const int val = (gid < NB_USERS) ? hist[gid] : 0;
    sd[t] = val;
    __syncthreads();
    for (int off = 1; off < 1024; off <<= 1) {
        const int x = (t >= off) ? sd[t - off] : 0;
        __syncthreads();
        sd[t] += x;
        __syncthreads();
    }
    if (gid < NB_USERS) starts[gid] = sd[t] - val;
    if (t == 1023) bsum[blockIdx.x] = sd[t];
}

__global__ void scan2_kernel(int* bsum, int nb)
{
    if (blockIdx.x == 0 && threadIdx.x == 0) {
        int run = 0;
        for (int i = 0; i < nb; ++i) { const int v = bsum[i]; bsum[i] = run; run += v; }
    }
}

__global__ __launch_bounds__(256) void scan3_kernel(
    const int* __restrict__ hist, int* __restrict__ starts,
    const int* __restrict__ bsum, int* __restrict__ cursor,
    float* __restrict__ nbrf)
{
    const int gid = blockIdx.x * 256 + threadIdx.x;
    if (gid >= NB_USERS) return;
    const int s = starts[gid] + bsum[gid >> 10];
    starts[gid] = s;
    cursor[gid] = s;
    nbrf[gid]   = (float)hist[gid];
}

__global__ __launch_bounds__(256) void scatter_kernel(
    const int* __restrict__ du, const int* __restrict__ dm,
    const float* __restrict__ dr, int* __restrict__ cursor,
    uint2* __restrict__ sorted_ur)
{
    int i = blockIdx.x * 256 + threadIdx.x;
    const int stride = gridDim.x * 256;
    for (; i < NPTS; i += stride) {
        const int u = du[i];
        const int pos = atomicAdd(&cursor[u], 1);
        const unsigned rq = (unsigned)(int)fmaf(dr[i], (float)RQ_LEVELS / 5.0f, 0.5f);
        sorted_ur[pos] = make_uint2(((unsigned)u << 15) | (unsigned)dm[i], rq);
    }
}

// ---------------- rbm_saved: rows n < 20000 from the UNSORTED stream ----------------
// (reference quirk: rbm indexed by movie id as a data-row index)

__global__ __launch_bounds__(256, 3) void rbm_saved_kernel(
    const int* __restrict__ dm, const float* __restrict__ dr,
    const float* __restrict__ mf, const float* __restrict__ rtab,
    const float* __restrict__ W_c, const float* __restrict__ b_c,
    float* __restrict__ rbm_saved)
{
    const int lane = threadIdx.x & 63;
    const int wave = blockIdx.x * (blockDim.x >> 6) + (threadIdx.x >> 6);
    const int NT = (NB_MOVIES + 63) / 64;      // 313
    if (wave >= NT) return;

    bf16x8 bfrag[4][2];
    #pragma unroll
    for (int nt = 0; nt < 4; ++nt)
        #pragma unroll
        for (int kt = 0; kt < 2; ++kt) {
            const float* wrow =
                &W_c[(nt * 16 + (lane & 15)) * KDIM + kt * 32 + (lane >> 4) * 8];
            #pragma unroll
            for (int e = 0; e < 8; ++e) bfrag[nt][kt][e] = (__bf16)wrow[e];
        }
    float bcv[4];
    #pragma unroll
    for (int nt = 0; nt < 4; ++nt) bcv[nt] = b_c[nt * 16 + (lane & 15)];

    const int base = wave * 64;
    const int koff = (lane >> 4) * 8;

    #pragma unroll 1
    for (int mt = 0; mt < 4; ++mt) {
        const int pg = base + mt * 16 + (lane & 15);
        int   m = 0;
        float r = 0.f;
        if (pg < NB_MOVIES) { m = dm[pg]; r = dr[pg]; }
        const int rq = (int)fmaf(r, (float)RQ_LEVELS / 5.0f, 0.5f);

        const float* mrow = mf   + (size_t)m  * KDIM + koff;
        const float* trow = rtab + (size_t)rq * KDIM + koff;
        const f32x4 m0 = *(const f32x4*)(mrow);
        const f32x4 m1 = *(const f32x4*)(mrow + 4);
        const f32x4 m2 = *(const f32x4*)(mrow + 32);
        const f32x4 m3 = *(const f32x4*)(mrow + 36);
        const f32x4 t0 = *(const f32x4*)(trow);
        const f32x4 t1 = *(const f32x4*)(trow + 4);
        const f32x4 t2 = *(const f32x4*)(trow + 32);
        const f32x4 t3 = *(const f32x4*)(trow + 36);

        bf16x8 a0, a1;
        #pragma unroll
        for (int e = 0; e < 4; ++e) {
            a0[e]     = (__bf16)(m0[e] * t0[e]);
            a0[e + 4] = (__bf16)(m1[e] * t1[e]);
            a1[e]     = (__bf16)(m2[e] * t2[e]);
            a1[e + 4] = (__bf16)(m3[e] * t3[e]);
        }

        f32x4 acc[4];
        #pragma unroll
        for (int nt = 0; nt < 4; ++nt) {
            acc[nt] = (f32x4){0.f, 0.f, 0.f, 0.f};
            acc[nt] = __builtin_amdgcn_mfma_f32_16x16x32_bf16(a0, bfrag[nt][0], acc[nt], 0, 0, 0);
            acc[nt] = __builtin_amdgcn_mfma_f32_16x16x32_bf16(a1, bfrag[nt][1], acc[nt], 0, 0, 0);
        }

        #pragma unroll
        for (int reg = 0; reg < 4; ++reg) {
            const int prow_g = base + mt * 16 + (lane >> 4) * 4 + reg;
            if (prow_g < NB_MOVIES) {
                #pragma unroll
                for (int nt = 0; nt < 4; ++nt) {
                    const float rbm = sigmoidf(acc[nt][reg] + bcv[nt]);
                    rbm_saved[(size_t)prow_g * KDIM + nt * 16 + (lane & 15)] = rbm;
                }
            }
        }
    }
}

// ---------------- phase 1: user-sorted stream, fragment-direct, segmented reduce ----------------

__global__ __launch_bounds__(256, 3) void phase1_sorted_kernel(
    const uint2* __restrict__ sorted_ur,
    const float* __restrict__ mf,
    const float* __restrict__ rtab,
    const float* __restrict__ W_c,
    const float* __restrict__ b_c,
    float* __restrict__ rbu)
{
    const int lane = threadIdx.x & 63;
    const int wave = blockIdx.x * (blockDim.x >> 6) + (threadIdx.x >> 6);
    const int nwav = gridDim.x * (blockDim.x >> 6);

    bf16x8 bfrag[4][2];
    #pragma unroll
    for (int nt = 0; nt < 4; ++nt)
        #pragma unroll
        for (int kt = 0; kt < 2; ++kt) {
            const float* wrow =
                &W_c[(nt * 16 + (lane & 15)) * KDIM + kt * 32 + (lane >> 4) * 8];
            #pragma unroll
            for (int e = 0; e < 8; ++e) bfrag[nt][kt][e] = (__bf16)wrow[e];
        }
    float bcv[4];
    #pragma unroll
    for (int nt = 0; nt < 4; ++nt) bcv[nt] = b_c[nt * 16 + (lane & 15)];

    const int koff = (lane >> 4) * 8;
    const int g    = lane >> 4;

    for (int it = wave; it < NTILES; it += nwav) {
        const int base = it * 64;

        #pragma unroll 1
        for (int mt = 0; mt < 4; ++mt) {
            // lane owns point p = mt*16 + (lane&15)  (4-way duplicated across groups)
            const uint2 ur = sorted_ur[base + mt * 16 + (lane & 15)];
            const unsigned u_at = ur.x >> 15;
            const int      m    = (int)(ur.x & 0x7fffu);
            const int      rq   = (int)ur.y;

            const float* mrow = mf   + (size_t)m  * KDIM + koff;
            const float* trow = rtab + (size_t)rq * KDIM + koff;
            const f32x4 m0 = *(const f32x4*)(mrow);
            const f32x4 m1 = *(const f32x4*)(mrow + 4);
            const f32x4 m2 = *(const f32x4*)(mrow + 32);
            const f32x4 m3 = *(const f32x4*)(mrow + 36);
            const f32x4 t0 = *(const f32x4*)(trow);
            const f32x4 t1 = *(const f32x4*)(trow + 4);
            const f32x4 t2 = *(const f32x4*)(trow + 32);
            const f32x4 t3 = *(const f32x4*)(trow + 36);

            // A fragments: lane holds point-row p, k = kt*32 + koff + e
            bf16x8 a0, a1;
            #pragma unroll
            for (int e = 0; e < 4; ++e) {
                a0[e]     = (__bf16)(m0[e] * t0[e]);
                a0[e + 4] = (__bf16)(m1[e] * t1[e]);
                a1[e]     = (__bf16)(m2[e] * t2[e]);
                a1[e + 4] = (__bf16)(m3[e] * t3[e]);
            }

            f32x4 acc[4];
            #pragma unroll
            for (int nt = 0; nt < 4; ++nt) {
                acc[nt] = (f32x4){0.f, 0.f, 0.f, 0.f};
                acc[nt] = __builtin_amdgcn_mfma_f32_16x16x32_bf16(a0, bfrag[nt][0], acc[nt], 0, 0, 0);
                acc[nt] = __builtin_amdgcn_mfma_f32_16x16x32_bf16(a1, bfrag[nt][1], acc[nt], 0, 0, 0);
            }

            // rbm[nt][reg]: point (g*4+reg), feature nt*16+(lane&15)
            float rbm[4][4];
            #pragma unroll
            for (int nt = 0; nt < 4; ++nt)
                #pragma unroll
                for (int reg = 0; reg < 4; ++reg)
                    rbm[nt][reg] = sigmoidf(acc[nt][reg] + bcv[nt]);

            // segment boundaries within this 16-point group
            const unsigned u_prev =
                (unsigned)__shfl((int)u_at, lane - 1, 64);   // valid where (lane&15)!=0
            const bool boundary = ((lane & 15) == 0) || (u_at != u_prev);
            unsigned long long bm = __ballot(boundary) & 0xFFFFull;

            while (bm) {
                const int s = __builtin_ctzll(bm);
                bm &= bm - 1;
                const int e = bm ? __builtin_ctzll(bm) : 16;
                const unsigned useg =
                    (unsigned)__builtin_amdgcn_readlane((int)u_at, s);

                const int lo = s - g * 4;
                const int hi = e - g * 4;
                float p0 = 0.f, p1 = 0.f, p2 = 0.f, p3 = 0.f;
                #pragma unroll
                for (int reg = 0; reg < 4; ++reg) {
                    const bool in = (reg >= lo) && (reg < hi);
                    p0 += in ? rbm[0][reg] : 0.f;
                    p1 += in ? rbm[1][reg] : 0.f;
                    p2 += in ? rbm[2][reg] : 0.f;
                    p3 += in ? rbm[3][reg] : 0.f;
                }
                p0 += __shfl_xor(p0, 16, 64); p0 += __shfl_xor(p0, 32, 64);
                p1 += __shfl_xor(p1, 16, 64); p1 += __shfl_xor(p1, 32, 64);
                p2 += __shfl_xor(p2, 16, 64); p2 += __shfl_xor(p2, 32, 64);
                p3 += __shfl_xor(p3, 16, 64); p3 += __shfl_xor(p3, 32, 64);

                const float v01 = (g & 1) ? p1 : p0;
                const float v23 = (g & 1) ? p3 : p2;
                const float val = (g & 2) ? v23 : v01;
                atomicAdd(&rbu[(size_t)useg * KDIM + lane], val);
            }
        }
    }
}

// ---------------- phase 2 ----------------

__global__ __launch_bounds__(256) void phase2_kernel(
    const int* __restrict__ x_users,
    const int* __restrict__ x_movies,
    const float* __restrict__ mf,
    const float* __restrict__ rbu,
    const float* __restrict__ nbrf,
    const float* __restrict__ rbm_saved,
    const float* __restrict__ w_out,
    const float* __restrict__ b_out,
    float* __restrict__ out)
{
    const int lane = threadIdx.x & 63;
    const int wave = blockIdx.x * (blockDim.x >> 6) + (threadIdx.x >> 6);
    if (wave >= NB_USERS) return;

    const int u  = x_users[wave];
    const int xm = x_movies[wave];

    const float nb = fmaxf(1.0f, nbrf[u] - 1.0f);
    const float uf = (rbu[(size_t)u * KDIM + lane] -
                      rbm_saved[(size_t)xm * KDIM + lane]) / nb;
    float p = mf[(size_t)xm * KDIM + lane] * uf;

    #pragma unroll
    for (int off = 32; off > 0; off >>= 1)
        p += __shfl_xor(p, off, 64);

    if (lane == 0)
        out[wave] = (p * (1.0f / 64.0f) * w_out[0] + b_out[0]) * 5.0f;
}

extern "C" void kernel_launch(void* const* d_in, const int* in_sizes, int n_in,
                              void* d_out, int out_size, void* d_ws, size_t ws_size,
                              hipStream_t stream) {
    const int*   x_users      = (const int*)  d_in[0];
    const int*   x_movies     = (const int*)  d_in[1];
    const int*   data_users   = (const int*)  d_in[2];
    const int*   data_movies  = (const int*)  d_in[3];
    const float* data_ratings = (const float*)d_in[4];
    const float* mf           = (const float*)d_in[5];
    const float* W_r          = (const float*)d_in[6];
    const float* b_r          = (const float*)d_in[7];
    const float* W_c          = (const float*)d_in[8];
    const float* b_c          = (const float*)d_in[9];
    const float* w_out        = (const float*)d_in[10];
    const float* b_out        = (const float*)d_in[11];
    float* out = (float*)d_out;

    // workspace layout (~50.5 MB)
    float*    rbu       = (float*)d_ws;                         // 6.4M f32
    float*    nbrf      = rbu + (size_t)NB_USERS * KDIM;        // 100K f32
    float*    rbm_saved = nbrf + NB_USERS;                      // 1.28M f32
    int*      hist      = (int*)(rbm_saved + (size_t)NB_MOVIES * KDIM);
    int*      starts    = hist + NB_USERS;
    int*      cursor    = starts + NB_USERS;
    int*      bsum      = cursor + NB_USERS;                    // 128 ints
    uint2*    sorted_ur = (uint2*)(bsum + 128);                 // 2M uint2
    float*    rtab      = (float*)(sorted_ur + NPTS);           // 8193*64 f32

    hipMemsetAsync(rbu, 0, (size_t)NB_USERS * KDIM * sizeof(float), stream);
    hipMemsetAsync(hist, 0, NB_USERS * sizeof(int), stream);

    rtab_kernel<<<((RQ_LEVELS + 1) * KDIM + 255) / 256, 256, 0, stream>>>(W_r, b_r, rtab);

    hist_kernel<<<2048, 256, 0, stream>>>(data_users, hist);

    const int nblk_scan = (NB_USERS + 1023) / 1024;             // 98
    scan1_kernel<<<nblk_scan, 1024, 0, stream>>>(hist, starts, bsum);
    scan2_kernel<<<1, 64, 0, stream>>>(bsum, nblk_scan);
    scan3_kernel<<<(NB_USERS + 255) / 256, 256, 0, stream>>>(hist, starts, bsum, cursor, nbrf);

    scatter_kernel<<<2048, 256, 0, stream>>>(
        data_users, data_movies, data_ratings, cursor, sorted_ur);

    rbm_saved_kernel<<<79, 256, 0, stream>>>(
        data_movies, data_ratings, mf, rtab, W_c, b_c, rbm_saved);

    phase1_sorted_kernel<<<1024, 256, 0, stream>>>(
        sorted_ur, mf, rtab, W_c, b_c, rbu);

    phase2_kernel<<<(NB_USERS * 64 + 255) / 256, 256, 0, stream>>>(
        x_users, x_movies, mf, rbu, nbrf, rbm_saved, w_out, b_out, out);
}

// Round 5
// 254.354 us; speedup vs baseline: 2.7681x; 1.6533x over previous
//
#include <hip/hip_runtime.h>

#define NB_USERS 100000
#define NB_MOVIES 20000
#define KDIM 64
#define NPTS 2000000
#define NTILES (NPTS / 64)
#define RQ_LEVELS 8192            // rating quantization; table rows = RQ_LEVELS+1
#define NBUCK 391                 // ceil(NB_USERS / 256) user buckets (256 users each)
#define CHUNK 4096                // points per binA block
#define NCHUNK ((NPTS + CHUNK - 1) / CHUNK)
#define BCAP 6400                 // pass-B LDS capacity (mean 5115, sigma ~71 -> 18 sigma)

typedef __bf16 bf16x8 __attribute__((ext_vector_type(8)));
typedef float  f32x4  __attribute__((ext_vector_type(4)));

__device__ __forceinline__ float sigmoidf(float z) {
    return 1.0f / (1.0f + __expf(-z));
}

// ---------------- rating-embedding table ----------------
__global__ __launch_bounds__(256) void rtab_kernel(
    const float* __restrict__ W_r, const float* __restrict__ b_r,
    float* __restrict__ rtab)
{
    const int idx = blockIdx.x * 256 + threadIdx.x;
    const int total = (RQ_LEVELS + 1) * KDIM;
    if (idx >= total) return;
    const int q = idx >> 6, k = idx & 63;
    rtab[idx] = sigmoidf(fmaf((float)q * (1.0f / RQ_LEVELS), W_r[k], b_r[k]));
}

// ---------------- bucket histogram (391 coarse buckets) ----------------
__global__ __launch_bounds__(256) void bucket_hist_kernel(
    const int* __restrict__ du, int* __restrict__ bhist)
{
    __shared__ int h[NBUCK];
    for (int b = threadIdx.x; b < NBUCK; b += 256) h[b] = 0;
    __syncthreads();
    int i = blockIdx.x * 256 + threadIdx.x;
    const int stride = gridDim.x * 256;
    for (; i < NPTS; i += stride) atomicAdd(&h[du[i] >> 8], 1);
    __syncthreads();
    for (int b = threadIdx.x; b < NBUCK; b += 256)
        if (h[b]) atomicAdd(&bhist[b], h[b]);
}

// ---------------- bucket scan (1 block) ----------------
__global__ __launch_bounds__(256) void bscan_kernel(
    const int* __restrict__ bhist, int* __restrict__ bstart, int* __restrict__ bcursor)
{
    __shared__ int s[512];
    const int t = threadIdx.x;
    const int v0 = (t < NBUCK) ? bhist[t] : 0;
    const int v1 = (t + 256 < NBUCK) ? bhist[t + 256] : 0;
    s[t] = v0; s[t + 256] = v1;
    __syncthreads();
    for (int d = 1; d < 512; d <<= 1) {
        const int a0 = (t >= d) ? s[t - d] : 0;
        const int a1 = (t + 256 >= d) ? s[t + 256 - d] : 0;
        __syncthreads();
        s[t] += a0; s[t + 256] += a1;
        __syncthreads();
    }
    if (t < NBUCK)       { bstart[t]       = s[t] - v0;       bcursor[t]       = s[t] - v0; }
    if (t + 256 < NBUCK) { bstart[t + 256] = s[t + 256] - v1; bcursor[t + 256] = s[t + 256] - v1; }
}

// ---------------- pass A: bin points by bucket, LDS-grouped writes ----------------
__global__ __launch_bounds__(256) void binA_kernel(
    const int* __restrict__ du, const int* __restrict__ dm,
    const float* __restrict__ dr,
    int* __restrict__ bcursor, uint2* __restrict__ binned)
{
    __shared__ uint2 buf[CHUNK];          // 32 KB
    __shared__ int cnt[NBUCK];
    __shared__ int scn[512];
    __shared__ int sbase[NBUCK];
    __shared__ int cur[NBUCK];
    __shared__ int gbase[NBUCK];

    const int t  = threadIdx.x;
    const int c0 = blockIdx.x * CHUNK;
    const int n  = min(CHUNK, NPTS - c0);

    for (int b = t; b < NBUCK; b += 256) cnt[b] = 0;
    __syncthreads();

    uint2 p[CHUNK / 256];
    #pragma unroll
    for (int j = 0; j < CHUNK / 256; ++j) {
        const int i = c0 + j * 256 + t;
        if (j * 256 + t < n) {
            const unsigned u  = (unsigned)du[i];
            const unsigned m  = (unsigned)dm[i];
            const unsigned rq = (unsigned)(int)fmaf(dr[i], (float)RQ_LEVELS / 5.0f, 0.5f);
            p[j] = make_uint2((u << 15) | m, rq);
            atomicAdd(&cnt[u >> 8], 1);
        } else {
            p[j] = make_uint2(0xFFFFFFFFu, 0u);   // invalid (u would be 131071 > NB_USERS)
        }
    }
    __syncthreads();

    // exclusive scan of cnt -> sbase (Hillis-Steele over 512, 2 elems/thread)
    scn[t]       = (t < NBUCK) ? cnt[t] : 0;
    scn[t + 256] = (t + 256 < NBUCK) ? cnt[t + 256] : 0;
    __syncthreads();
    for (int d = 1; d < 512; d <<= 1) {
        const int a0 = (t >= d) ? scn[t - d] : 0;
        const int a1 = (t + 256 >= d) ? scn[t + 256 - d] : 0;
        __syncthreads();
        scn[t] += a0; scn[t + 256] += a1;
        __syncthreads();
    }
    for (int b = t; b < NBUCK; b += 256) {
        const int e = scn[b] - cnt[b];
        sbase[b] = e;
        cur[b]   = e;
        if (cnt[b] > 0) gbase[b] = atomicAdd(&bcursor[b], cnt[b]);
    }
    __syncthreads();

    // place into LDS grouped by bucket
    #pragma unroll
    for (int j = 0; j < CHUNK / 256; ++j) {
        if (p[j].x != 0xFFFFFFFFu) {
            const int b   = p[j].x >> 23;     // (u>>8)
            const int pos = atomicAdd(&cur[b], 1);
            buf[pos] = p[j];
        }
    }
    __syncthreads();

    // write grouped runs to global (coalesced within runs)
    for (int i = t; i < n; i += 256) {
        const uint2 q = buf[i];
        const int b = q.x >> 23;
        binned[gbase[b] + (i - sbase[b])] = q;
    }
}

// ---------------- pass B: sort bucket by user in LDS, coalesced write + nbrf ----------------
__global__ __launch_bounds__(256) void binB_kernel(
    const uint2* __restrict__ binned,
    const int* __restrict__ bhist, const int* __restrict__ bstart,
    uint2* __restrict__ sorted, float* __restrict__ nbrf)
{
    __shared__ uint2 buf[BCAP];           // 51.2 KB
    __shared__ int cnt[256];
    __shared__ int cur[256];

    const int t  = threadIdx.x;
    const int b  = blockIdx.x;
    const int n  = bhist[b];
    const int s0 = bstart[b];

    cnt[t] = 0;
    __syncthreads();

    for (int i = t; i < n; i += 256)
        atomicAdd(&cnt[(binned[s0 + i].x >> 15) & 255], 1);
    __syncthreads();

    // per-user counts ARE the global histogram for this bucket's users
    const int uid = (b << 8) + t;
    if (uid < NB_USERS) nbrf[uid] = (float)cnt[t];

    // exclusive scan of cnt (Hillis-Steele over 256)
    const int inc = cnt[t];
    cur[t] = inc;
    __syncthreads();
    for (int d = 1; d < 256; d <<= 1) {
        const int a = (t >= d) ? cur[t - d] : 0;
        __syncthreads();
        cur[t] += a;
        __syncthreads();
    }
    const int excl = cur[t] - inc;
    __syncthreads();
    cur[t] = excl;
    __syncthreads();

    for (int i = t; i < n; i += 256) {
        const uint2 q  = binned[s0 + i];
        const int  lu  = (q.x >> 15) & 255;
        const int  pos = atomicAdd(&cur[lu], 1);
        buf[pos] = q;
    }
    __syncthreads();

    for (int i = t; i < n; i += 256)
        sorted[s0 + i] = buf[i];
}

// ---------------- rbm_saved: rows n < 20000 from the UNSORTED stream ----------------
__global__ __launch_bounds__(256, 3) void rbm_saved_kernel(
    const int* __restrict__ dm, const float* __restrict__ dr,
    const float* __restrict__ mf, const float* __restrict__ rtab,
    const float* __restrict__ W_c, const float* __restrict__ b_c,
    float* __restrict__ rbm_saved)
{
    const int lane = threadIdx.x & 63;
    const int wave = blockIdx.x * (blockDim.x >> 6) + (threadIdx.x >> 6);
    const int NT = (NB_MOVIES + 63) / 64;      // 313
    if (wave >= NT) return;

    bf16x8 bfrag[4][2];
    #pragma unroll
    for (int nt = 0; nt < 4; ++nt)
        #pragma unroll
        for (int kt = 0; kt < 2; ++kt) {
            const float* wrow =
                &W_c[(nt * 16 + (lane & 15)) * KDIM + kt * 32 + (lane >> 4) * 8];
            #pragma unroll
            for (int e = 0; e < 8; ++e) bfrag[nt][kt][e] = (__bf16)wrow[e];
        }
    float bcv[4];
    #pragma unroll
    for (int nt = 0; nt < 4; ++nt) bcv[nt] = b_c[nt * 16 + (lane & 15)];

    const int base = wave * 64;
    const int koff = (lane >> 4) * 8;

    #pragma unroll 1
    for (int mt = 0; mt < 4; ++mt) {
        const int pg = base + mt * 16 + (lane & 15);
        int   m = 0;
        float r = 0.f;
        if (pg < NB_MOVIES) { m = dm[pg]; r = dr[pg]; }
        const int rq = (int)fmaf(r, (float)RQ_LEVELS / 5.0f, 0.5f);

        const float* mrow = mf   + (size_t)m  * KDIM + koff;
        const float* trow = rtab + (size_t)rq * KDIM + koff;
        const f32x4 m0 = *(const f32x4*)(mrow);
        const f32x4 m1 = *(const f32x4*)(mrow + 4);
        const f32x4 m2 = *(const f32x4*)(mrow + 32);
        const f32x4 m3 = *(const f32x4*)(mrow + 36);
        const f32x4 t0 = *(const f32x4*)(trow);
        const f32x4 t1 = *(const f32x4*)(trow + 4);
        const f32x4 t2 = *(const f32x4*)(trow + 32);
        const f32x4 t3 = *(const f32x4*)(trow + 36);

        bf16x8 a0, a1;
        #pragma unroll
        for (int e = 0; e < 4; ++e) {
            a0[e]     = (__bf16)(m0[e] * t0[e]);
            a0[e + 4] = (__bf16)(m1[e] * t1[e]);
            a1[e]     = (__bf16)(m2[e] * t2[e]);
            a1[e + 4] = (__bf16)(m3[e] * t3[e]);
        }

        f32x4 acc[4];
        #pragma unroll
        for (int nt = 0; nt < 4; ++nt) {
            acc[nt] = (f32x4){0.f, 0.f, 0.f, 0.f};
            acc[nt] = __builtin_amdgcn_mfma_f32_16x16x32_bf16(a0, bfrag[nt][0], acc[nt], 0, 0, 0);
            acc[nt] = __builtin_amdgcn_mfma_f32_16x16x32_bf16(a1, bfrag[nt][1], acc[nt], 0, 0, 0);
        }

        #pragma unroll
        for (int reg = 0; reg < 4; ++reg) {
            const int prow_g = base + mt * 16 + (lane >> 4) * 4 + reg;
            if (prow_g < NB_MOVIES) {
                #pragma unroll
                for (int nt = 0; nt < 4; ++nt) {
                    const float rbm = sigmoidf(acc[nt][reg] + bcv[nt]);
                    rbm_saved[(size_t)prow_g * KDIM + nt * 16 + (lane & 15)] = rbm;
                }
            }
        }
    }
}

// ---------------- phase 1: user-sorted stream, fragment-direct, segmented reduce ----------------
__global__ __launch_bounds__(256, 3) void phase1_sorted_kernel(
    const uint2* __restrict__ sorted_ur,
    const float* __restrict__ mf,
    const float* __restrict__ rtab,
    const float* __restrict__ W_c,
    const float* __restrict__ b_c,
    float* __restrict__ rbu)
{
    const int lane = threadIdx.x & 63;
    const int wave = blockIdx.x * (blockDim.x >> 6) + (threadIdx.x >> 6);
    const int nwav = gridDim.x * (blockDim.x >> 6);

    bf16x8 bfrag[4][2];
    #pragma unroll
    for (int nt = 0; nt < 4; ++nt)
        #pragma unroll
        for (int kt = 0; kt < 2; ++kt) {
            const float* wrow =
                &W_c[(nt * 16 + (lane & 15)) * KDIM + kt * 32 + (lane >> 4) * 8];
            #pragma unroll
            for (int e = 0; e < 8; ++e) bfrag[nt][kt][e] = (__bf16)wrow[e];
        }
    float bcv[4];
    #pragma unroll
    for (int nt = 0; nt < 4; ++nt) bcv[nt] = b_c[nt * 16 + (lane & 15)];

    const int koff = (lane >> 4) * 8;
    const int g    = lane >> 4;

    for (int it = wave; it < NTILES; it += nwav) {
        const int base = it * 64;

        #pragma unroll 1
        for (int mt = 0; mt < 4; ++mt) {
            const uint2 ur = sorted_ur[base + mt * 16 + (lane & 15)];
            const unsigned u_at = ur.x >> 15;
            const int      m    = (int)(ur.x & 0x7fffu);
            const int      rq   = (int)ur.y;

            const float* mrow = mf   + (size_t)m  * KDIM + koff;
            const float* trow = rtab + (size_t)rq * KDIM + koff;
            const f32x4 m0 = *(const f32x4*)(mrow);
            const f32x4 m1 = *(const f32x4*)(mrow + 4);
            const f32x4 m2 = *(const f32x4*)(mrow + 32);
            const f32x4 m3 = *(const f32x4*)(mrow + 36);
            const f32x4 t0 = *(const f32x4*)(trow);
            const f32x4 t1 = *(const f32x4*)(trow + 4);
            const f32x4 t2 = *(const f32x4*)(trow + 32);
            const f32x4 t3 = *(const f32x4*)(trow + 36);

            bf16x8 a0, a1;
            #pragma unroll
            for (int e = 0; e < 4; ++e) {
                a0[e]     = (__bf16)(m0[e] * t0[e]);
                a0[e + 4] = (__bf16)(m1[e] * t1[e]);
                a1[e]     = (__bf16)(m2[e] * t2[e]);
                a1[e + 4] = (__bf16)(m3[e] * t3[e]);
            }

            f32x4 acc[4];
            #pragma unroll
            for (int nt = 0; nt < 4; ++nt) {
                acc[nt] = (f32x4){0.f, 0.f, 0.f, 0.f};
                acc[nt] = __builtin_amdgcn_mfma_f32_16x16x32_bf16(a0, bfrag[nt][0], acc[nt], 0, 0, 0);
                acc[nt] = __builtin_amdgcn_mfma_f32_16x16x32_bf16(a1, bfrag[nt][1], acc[nt], 0, 0, 0);
            }

            float rbm[4][4];
            #pragma unroll
            for (int nt = 0; nt < 4; ++nt)
                #pragma unroll
                for (int reg = 0; reg < 4; ++reg)
                    rbm[nt][reg] = sigmoidf(acc[nt][reg] + bcv[nt]);

            const unsigned u_prev =
                (unsigned)__shfl((int)u_at, lane - 1, 64);
            const bool boundary = ((lane & 15) == 0) || (u_at != u_prev);
            unsigned long long bm = __ballot(boundary) & 0xFFFFull;

            while (bm) {
                const int s = __builtin_ctzll(bm);
                bm &= bm - 1;
                const int e = bm ? __builtin_ctzll(bm) : 16;
                const unsigned useg =
                    (unsigned)__builtin_amdgcn_readlane((int)u_at, s);

                const int lo = s - g * 4;
                const int hi = e - g * 4;
                float p0 = 0.f, p1 = 0.f, p2 = 0.f, p3 = 0.f;
                #pragma unroll
                for (int reg = 0; reg < 4; ++reg) {
                    const bool in = (reg >= lo) && (reg < hi);
                    p0 += in ? rbm[0][reg] : 0.f;
                    p1 += in ? rbm[1][reg] : 0.f;
                    p2 += in ? rbm[2][reg] : 0.f;
                    p3 += in ? rbm[3][reg] : 0.f;
                }
                p0 += __shfl_xor(p0, 16, 64); p0 += __shfl_xor(p0, 32, 64);
                p1 += __shfl_xor(p1, 16, 64); p1 += __shfl_xor(p1, 32, 64);
                p2 += __shfl_xor(p2, 16, 64); p2 += __shfl_xor(p2, 32, 64);
                p3 += __shfl_xor(p3, 16, 64); p3 += __shfl_xor(p3, 32, 64);

                const float v01 = (g & 1) ? p1 : p0;
                const float v23 = (g & 1) ? p3 : p2;
                const float val = (g & 2) ? v23 : v01;
                atomicAdd(&rbu[(size_t)useg * KDIM + lane], val);
            }
        }
    }
}

// ---------------- phase 2 ----------------
__global__ __launch_bounds__(256) void phase2_kernel(
    const int* __restrict__ x_users,
    const int* __restrict__ x_movies,
    const float* __restrict__ mf,
    const float* __restrict__ rbu,
    const float* __restrict__ nbrf,
    const float* __restrict__ rbm_saved,
    const float* __restrict__ w_out,
    const float* __restrict__ b_out,
    float* __restrict__ out)
{
    const int lane = threadIdx.x & 63;
    const int wave = blockIdx.x * (blockDim.x >> 6) + (threadIdx.x >> 6);
    if (wave >= NB_USERS) return;

    const int u  = x_users[wave];
    const int xm = x_movies[wave];

    const float nb = fmaxf(1.0f, nbrf[u] - 1.0f);
    const float uf = (rbu[(size_t)u * KDIM + lane] -
                      rbm_saved[(size_t)xm * KDIM + lane]) / nb;
    float p = mf[(size_t)xm * KDIM + lane] * uf;

    #pragma unroll
    for (int off = 32; off > 0; off >>= 1)
        p += __shfl_xor(p, off, 64);

    if (lane == 0)
        out[wave] = (p * (1.0f / 64.0f) * w_out[0] + b_out[0]) * 5.0f;
}

extern "C" void kernel_launch(void* const* d_in, const int* in_sizes, int n_in,
                              void* d_out, int out_size, void* d_ws, size_t ws_size,
                              hipStream_t stream) {
    const int*   x_users      = (const int*)  d_in[0];
    const int*   x_movies     = (const int*)  d_in[1];
    const int*   data_users   = (const int*)  d_in[2];
    const int*   data_movies  = (const int*)  d_in[3];
    const float* data_ratings = (const float*)d_in[4];
    const float* mf           = (const float*)d_in[5];
    const float* W_r          = (const float*)d_in[6];
    const float* b_r          = (const float*)d_in[7];
    const float* W_c          = (const float*)d_in[8];
    const float* b_c          = (const float*)d_in[9];
    const float* w_out        = (const float*)d_in[10];
    const float* b_out        = (const float*)d_in[11];
    float* out = (float*)d_out;

    // workspace layout (~49.3 MB):
    //   rbu       : 6.40M f32 (25.6 MB)   [first 16 MB aliased as `binned` during sort]
    //   nbrf      : 100K f32
    //   rbm_saved : 1.28M f32
    //   sorted_ur : 2M uint2 (16 MB)
    //   rtab      : 8193*64 f32 (2.1 MB)
    //   bhist/bstart/bcursor : 3*391 ints
    float* rbu       = (float*)d_ws;
    uint2* binned    = (uint2*)d_ws;                       // alias (consumed before rbu memset)
    float* nbrf      = rbu + (size_t)NB_USERS * KDIM;
    float* rbm_saved = nbrf + NB_USERS;
    uint2* sorted_ur = (uint2*)(rbm_saved + (size_t)NB_MOVIES * KDIM);
    float* rtab      = (float*)(sorted_ur + NPTS);
    int*   bhist     = (int*)(rtab + (size_t)(RQ_LEVELS + 1) * KDIM);
    int*   bstart    = bhist + NBUCK;
    int*   bcursor   = bstart + NBUCK;

    hipMemsetAsync(bhist, 0, NBUCK * sizeof(int), stream);

    rtab_kernel<<<((RQ_LEVELS + 1) * KDIM + 255) / 256, 256, 0, stream>>>(W_r, b_r, rtab);

    bucket_hist_kernel<<<1024, 256, 0, stream>>>(data_users, bhist);
    bscan_kernel<<<1, 256, 0, stream>>>(bhist, bstart, bcursor);

    binA_kernel<<<NCHUNK, 256, 0, stream>>>(
        data_users, data_movies, data_ratings, bcursor, binned);

    rbm_saved_kernel<<<79, 256, 0, stream>>>(
        data_movies, data_ratings, mf, rtab, W_c, b_c, rbm_saved);

    binB_kernel<<<NBUCK, 256, 0, stream>>>(binned, bhist, bstart, sorted_ur, nbrf);

    // binned fully consumed -> safe to zero rbu (aliases it)
    hipMemsetAsync(rbu, 0, (size_t)NB_USERS * KDIM * sizeof(float), stream);

    phase1_sorted_kernel<<<1024, 256, 0, stream>>>(
        sorted_ur, mf, rtab, W_c, b_c, rbu);

    phase2_kernel<<<(NB_USERS * 64 + 255) / 256, 256, 0, stream>>>(
        x_users, x_movies, mf, rbu, nbrf, rbm_saved, w_out, b_out, out);
}

// Round 6
// 215.716 us; speedup vs baseline: 3.2639x; 1.1791x over previous
//
#include <hip/hip_runtime.h>

#define NB_USERS 100000
#define NB_MOVIES 20000
#define KDIM 64
#define NPTS 2000000
#define NTILES (NPTS / 64)
#define RQ_LEVELS 8192            // rating quantization; table rows = RQ_LEVELS+1
#define NBUCK 391                 // ceil(NB_USERS / 256) user buckets (256 users each)
#define CHUNK 4096                // points per binA block
#define NCHUNK ((NPTS + CHUNK - 1) / CHUNK)
#define BCAP 6400                 // pass-B LDS capacity (mean 5115, sigma ~71 -> 18 sigma)

typedef _Float16 f16x8 __attribute__((ext_vector_type(8)));
typedef float    f32x4 __attribute__((ext_vector_type(4)));

__device__ __forceinline__ float sigmoidf(float z) {
    return 1.0f / (1.0f + __expf(-z));
}

// ---------------- prep: f16 tables ----------------

__global__ __launch_bounds__(256) void mf16_kernel(
    const float* __restrict__ mf, _Float16* __restrict__ mf16)
{
    const int idx = blockIdx.x * 256 + threadIdx.x;
    if (idx < NB_MOVIES * KDIM) mf16[idx] = (_Float16)mf[idx];
}

// rtab16[q][k] = sigmoid((q/8192)*W_r[k] + b_r[k]) as f16
__global__ __launch_bounds__(256) void rtab16_kernel(
    const float* __restrict__ W_r, const float* __restrict__ b_r,
    _Float16* __restrict__ rtab16)
{
    const int idx = blockIdx.x * 256 + threadIdx.x;
    const int total = (RQ_LEVELS + 1) * KDIM;
    if (idx >= total) return;
    const int q = idx >> 6, k = idx & 63;
    rtab16[idx] = (_Float16)sigmoidf(fmaf((float)q * (1.0f / RQ_LEVELS), W_r[k], b_r[k]));
}

// W_c^T MFMA B-fragments, f16, laid out [ntkt][lane][8] for linear LDS copy.
// fragment: lane l, elem e = W_c[nt*16 + (l&15)][kt*32 + (l>>4)*8 + e]
__global__ __launch_bounds__(256) void wcfrag_kernel(
    const float* __restrict__ W_c, _Float16* __restrict__ wcfrag)
{
    const int idx = blockIdx.x * 256 + threadIdx.x;   // [0, 512)
    if (idx >= 8 * 64) return;
    const int ntkt = idx >> 6;
    const int nt = ntkt >> 1, kt = ntkt & 1;
    const int lane = idx & 63;
    const float* src = &W_c[(nt * 16 + (lane & 15)) * KDIM + kt * 32 + (lane >> 4) * 8];
    _Float16* dst = wcfrag + (size_t)ntkt * 512 + lane * 8;
    #pragma unroll
    for (int e = 0; e < 8; ++e) dst[e] = (_Float16)src[e];
}

// ---------------- bucket histogram (391 coarse buckets) ----------------
__global__ __launch_bounds__(256) void bucket_hist_kernel(
    const int* __restrict__ du, int* __restrict__ bhist)
{
    __shared__ int h[NBUCK];
    for (int b = threadIdx.x; b < NBUCK; b += 256) h[b] = 0;
    __syncthreads();
    int i = blockIdx.x * 256 + threadIdx.x;
    const int stride = gridDim.x * 256;
    for (; i < NPTS; i += stride) atomicAdd(&h[du[i] >> 8], 1);
    __syncthreads();
    for (int b = threadIdx.x; b < NBUCK; b += 256)
        if (h[b]) atomicAdd(&bhist[b], h[b]);
}

// ---------------- bucket scan (1 block) ----------------
__global__ __launch_bounds__(256) void bscan_kernel(
    const int* __restrict__ bhist, int* __restrict__ bstart, int* __restrict__ bcursor)
{
    __shared__ int s[512];
    const int t = threadIdx.x;
    const int v0 = (t < NBUCK) ? bhist[t] : 0;
    const int v1 = (t + 256 < NBUCK) ? bhist[t + 256] : 0;
    s[t] = v0; s[t + 256] = v1;
    __syncthreads();
    for (int d = 1; d < 512; d <<= 1) {
        const int a0 = (t >= d) ? s[t - d] : 0;
        const int a1 = (t + 256 >= d) ? s[t + 256 - d] : 0;
        __syncthreads();
        s[t] += a0; s[t + 256] += a1;
        __syncthreads();
    }
    if (t < NBUCK)       { bstart[t]       = s[t] - v0;       bcursor[t]       = s[t] - v0; }
    if (t + 256 < NBUCK) { bstart[t + 256] = s[t + 256] - v1; bcursor[t + 256] = s[t + 256] - v1; }
}

// ---------------- pass A: bin points by bucket, LDS-grouped writes ----------------
__global__ __launch_bounds__(256) void binA_kernel(
    const int* __restrict__ du, const int* __restrict__ dm,
    const float* __restrict__ dr,
    int* __restrict__ bcursor, uint2* __restrict__ binned)
{
    __shared__ uint2 buf[CHUNK];          // 32 KB
    __shared__ int cnt[NBUCK];
    __shared__ int scn[512];
    __shared__ int sbase[NBUCK];
    __shared__ int cur[NBUCK];
    __shared__ int gbase[NBUCK];

    const int t  = threadIdx.x;
    const int c0 = blockIdx.x * CHUNK;
    const int n  = min(CHUNK, NPTS - c0);

    for (int b = t; b < NBUCK; b += 256) cnt[b] = 0;
    __syncthreads();

    uint2 p[CHUNK / 256];
    #pragma unroll
    for (int j = 0; j < CHUNK / 256; ++j) {
        const int i = c0 + j * 256 + t;
        if (j * 256 + t < n) {
            const unsigned u  = (unsigned)du[i];
            const unsigned m  = (unsigned)dm[i];
            const unsigned rq = (unsigned)(int)fmaf(dr[i], (float)RQ_LEVELS / 5.0f, 0.5f);
            p[j] = make_uint2((u << 15) | m, rq);
            atomicAdd(&cnt[u >> 8], 1);
        } else {
            p[j] = make_uint2(0xFFFFFFFFu, 0u);
        }
    }
    __syncthreads();

    scn[t]       = (t < NBUCK) ? cnt[t] : 0;
    scn[t + 256] = (t + 256 < NBUCK) ? cnt[t + 256] : 0;
    __syncthreads();
    for (int d = 1; d < 512; d <<= 1) {
        const int a0 = (t >= d) ? scn[t - d] : 0;
        const int a1 = (t + 256 >= d) ? scn[t + 256 - d] : 0;
        __syncthreads();
        scn[t] += a0; scn[t + 256] += a1;
        __syncthreads();
    }
    for (int b = t; b < NBUCK; b += 256) {
        const int e = scn[b] - cnt[b];
        sbase[b] = e;
        cur[b]   = e;
        if (cnt[b] > 0) gbase[b] = atomicAdd(&bcursor[b], cnt[b]);
    }
    __syncthreads();

    #pragma unroll
    for (int j = 0; j < CHUNK / 256; ++j) {
        if (p[j].x != 0xFFFFFFFFu) {
            const int b   = p[j].x >> 23;
            const int pos = atomicAdd(&cur[b], 1);
            buf[pos] = p[j];
        }
    }
    __syncthreads();

    for (int i = t; i < n; i += 256) {
        const uint2 q = buf[i];
        const int b = q.x >> 23;
        binned[gbase[b] + (i - sbase[b])] = q;
    }
}

// ---------------- pass B: sort bucket by user in LDS, coalesced write + nbrf ----------------
__global__ __launch_bounds__(256) void binB_kernel(
    const uint2* __restrict__ binned,
    const int* __restrict__ bhist, const int* __restrict__ bstart,
    uint2* __restrict__ sorted, float* __restrict__ nbrf)
{
    __shared__ uint2 buf[BCAP];           // 51.2 KB
    __shared__ int cnt[256];
    __shared__ int cur[256];

    const int t  = threadIdx.x;
    const int b  = blockIdx.x;
    const int n  = bhist[b];
    const int s0 = bstart[b];

    cnt[t] = 0;
    __syncthreads();

    for (int i = t; i < n; i += 256)
        atomicAdd(&cnt[(binned[s0 + i].x >> 15) & 255], 1);
    __syncthreads();

    const int uid = (b << 8) + t;
    if (uid < NB_USERS) nbrf[uid] = (float)cnt[t];

    const int inc = cnt[t];
    cur[t] = inc;
    __syncthreads();
    for (int d = 1; d < 256; d <<= 1) {
        const int a = (t >= d) ? cur[t - d] : 0;
        __syncthreads();
        cur[t] += a;
        __syncthreads();
    }
    const int excl = cur[t] - inc;
    __syncthreads();
    cur[t] = excl;
    __syncthreads();

    for (int i = t; i < n; i += 256) {
        const uint2 q  = binned[s0 + i];
        const int  lu  = (q.x >> 15) & 255;
        const int  pos = atomicAdd(&cur[lu], 1);
        buf[pos] = q;
    }
    __syncthreads();

    for (int i = t; i < n; i += 256)
        sorted[s0 + i] = buf[i];
}

// ---------------- rbm_saved: rows n < 20000 from the UNSORTED stream (f16 path) ----------------
__global__ __launch_bounds__(256) void rbm_saved_kernel(
    const int* __restrict__ dm, const float* __restrict__ dr,
    const _Float16* __restrict__ mf16, const _Float16* __restrict__ rtab16,
    const _Float16* __restrict__ wcfrag, const float* __restrict__ b_c,
    float* __restrict__ rbm_saved)
{
    __shared__ _Float16 bsh[8 * 512];     // 8 KB: W_c fragments
    for (int i = threadIdx.x; i < 512; i += 256)
        ((f16x8*)bsh)[i] = ((const f16x8*)wcfrag)[i];
    __syncthreads();

    const int lane = threadIdx.x & 63;
    const int wave = blockIdx.x * (blockDim.x >> 6) + (threadIdx.x >> 6);
    const int NT = (NB_MOVIES + 63) / 64;      // 313
    if (wave >= NT) return;

    float bcv[4];
    #pragma unroll
    for (int nt = 0; nt < 4; ++nt) bcv[nt] = b_c[nt * 16 + (lane & 15)];

    const int base = wave * 64;
    const int koff = (lane >> 4) * 8;

    #pragma unroll 1
    for (int mt = 0; mt < 4; ++mt) {
        const int pg = base + mt * 16 + (lane & 15);
        int   m = 0;
        float r = 0.f;
        if (pg < NB_MOVIES) { m = dm[pg]; r = dr[pg]; }
        const int rq = (int)fmaf(r, (float)RQ_LEVELS / 5.0f, 0.5f);

        const f16x8 ma = *(const f16x8*)(mf16   + (size_t)m  * KDIM + koff);
        const f16x8 mb = *(const f16x8*)(mf16   + (size_t)m  * KDIM + 32 + koff);
        const f16x8 ta = *(const f16x8*)(rtab16 + (size_t)rq * KDIM + koff);
        const f16x8 tb = *(const f16x8*)(rtab16 + (size_t)rq * KDIM + 32 + koff);
        const f16x8 a0 = ma * ta;
        const f16x8 a1 = mb * tb;

        f32x4 acc[4];
        #pragma unroll
        for (int nt = 0; nt < 4; ++nt) {
            const f16x8 b0 = *(const f16x8*)(bsh + (nt * 2 + 0) * 512 + lane * 8);
            const f16x8 b1 = *(const f16x8*)(bsh + (nt * 2 + 1) * 512 + lane * 8);
            acc[nt] = (f32x4){0.f, 0.f, 0.f, 0.f};
            acc[nt] = __builtin_amdgcn_mfma_f32_16x16x32_f16(a0, b0, acc[nt], 0, 0, 0);
            acc[nt] = __builtin_amdgcn_mfma_f32_16x16x32_f16(a1, b1, acc[nt], 0, 0, 0);
        }

        #pragma unroll
        for (int reg = 0; reg < 4; ++reg) {
            const int prow_g = base + mt * 16 + (lane >> 4) * 4 + reg;
            if (prow_g < NB_MOVIES) {
                #pragma unroll
                for (int nt = 0; nt < 4; ++nt) {
                    const float rbm = sigmoidf(acc[nt][reg] + bcv[nt]);
                    rbm_saved[(size_t)prow_g * KDIM + nt * 16 + (lane & 15)] = rbm;
                }
            }
        }
    }
}

// ---------------- phase 1: user-sorted stream, f16 fragment-direct, segmented reduce ----------------
__global__ __launch_bounds__(256, 4) void phase1_sorted_kernel(
    const uint2* __restrict__ sorted_ur,
    const _Float16* __restrict__ mf16,
    const _Float16* __restrict__ rtab16,
    const _Float16* __restrict__ wcfrag,
    const float* __restrict__ b_c,
    float* __restrict__ rbu)
{
    __shared__ _Float16 bsh[8 * 512];     // 8 KB: W_c fragments [ntkt][lane][8]
    for (int i = threadIdx.x; i < 512; i += 256)
        ((f16x8*)bsh)[i] = ((const f16x8*)wcfrag)[i];
    __syncthreads();

    const int lane = threadIdx.x & 63;
    const int wave = blockIdx.x * (blockDim.x >> 6) + (threadIdx.x >> 6);
    const int nwav = gridDim.x * (blockDim.x >> 6);

    float bcv[4];
    #pragma unroll
    for (int nt = 0; nt < 4; ++nt) bcv[nt] = b_c[nt * 16 + (lane & 15)];

    const int koff = (lane >> 4) * 8;
    const int g    = lane >> 4;

    for (int it = wave; it < NTILES; it += nwav) {
        const int base = it * 64;

        #pragma unroll 1
        for (int mt = 0; mt < 4; ++mt) {
            const uint2 ur = sorted_ur[base + mt * 16 + (lane & 15)];
            const unsigned u_at = ur.x >> 15;
            const int      m    = (int)(ur.x & 0x7fffu);
            const int      rq   = (int)ur.y;

            const f16x8 ma = *(const f16x8*)(mf16   + (size_t)m  * KDIM + koff);
            const f16x8 mb = *(const f16x8*)(mf16   + (size_t)m  * KDIM + 32 + koff);
            const f16x8 ta = *(const f16x8*)(rtab16 + (size_t)rq * KDIM + koff);
            const f16x8 tb = *(const f16x8*)(rtab16 + (size_t)rq * KDIM + 32 + koff);
            const f16x8 a0 = ma * ta;     // v_pk_mul_f16
            const f16x8 a1 = mb * tb;

            f32x4 acc[4];
            #pragma unroll
            for (int nt = 0; nt < 4; ++nt) {
                const f16x8 b0 = *(const f16x8*)(bsh + (nt * 2 + 0) * 512 + lane * 8);
                const f16x8 b1 = *(const f16x8*)(bsh + (nt * 2 + 1) * 512 + lane * 8);
                acc[nt] = (f32x4){0.f, 0.f, 0.f, 0.f};
                acc[nt] = __builtin_amdgcn_mfma_f32_16x16x32_f16(a0, b0, acc[nt], 0, 0, 0);
                acc[nt] = __builtin_amdgcn_mfma_f32_16x16x32_f16(a1, b1, acc[nt], 0, 0, 0);
            }

            // sigmoid in place: acc[nt][reg] = rbm for point (g*4+reg), feat nt*16+(lane&15)
            #pragma unroll
            for (int nt = 0; nt < 4; ++nt)
                #pragma unroll
                for (int reg = 0; reg < 4; ++reg)
                    acc[nt][reg] = sigmoidf(acc[nt][reg] + bcv[nt]);

            const unsigned u_prev =
                (unsigned)__shfl((int)u_at, lane - 1, 64);
            const bool boundary = ((lane & 15) == 0) || (u_at != u_prev);
            unsigned long long bm = __ballot(boundary) & 0xFFFFull;

            while (bm) {
                const int s = __builtin_ctzll(bm);
                bm &= bm - 1;
                const int e = bm ? __builtin_ctzll(bm) : 16;
                const unsigned useg =
                    (unsigned)__builtin_amdgcn_readlane((int)u_at, s);

                const int lo = s - g * 4;
                const int hi = e - g * 4;
                float p0 = 0.f, p1 = 0.f, p2 = 0.f, p3 = 0.f;
                #pragma unroll
                for (int reg = 0; reg < 4; ++reg) {
                    const bool in = (reg >= lo) && (reg < hi);
                    p0 += in ? acc[0][reg] : 0.f;
                    p1 += in ? acc[1][reg] : 0.f;
                    p2 += in ? acc[2][reg] : 0.f;
                    p3 += in ? acc[3][reg] : 0.f;
                }
                p0 += __shfl_xor(p0, 16, 64); p0 += __shfl_xor(p0, 32, 64);
                p1 += __shfl_xor(p1, 16, 64); p1 += __shfl_xor(p1, 32, 64);
                p2 += __shfl_xor(p2, 16, 64); p2 += __shfl_xor(p2, 32, 64);
                p3 += __shfl_xor(p3, 16, 64); p3 += __shfl_xor(p3, 32, 64);

                const float v01 = (g & 1) ? p1 : p0;
                const float v23 = (g & 1) ? p3 : p2;
                const float val = (g & 2) ? v23 : v01;
                atomicAdd(&rbu[(size_t)useg * KDIM + lane], val);
            }
        }
    }
}

// ---------------- phase 2 ----------------
__global__ __launch_bounds__(256) void phase2_kernel(
    const int* __restrict__ x_users,
    const int* __restrict__ x_movies,
    const float* __restrict__ mf,
    const float* __restrict__ rbu,
    const float* __restrict__ nbrf,
    const float* __restrict__ rbm_saved,
    const float* __restrict__ w_out,
    const float* __restrict__ b_out,
    float* __restrict__ out)
{
    const int lane = threadIdx.x & 63;
    const int wave = blockIdx.x * (blockDim.x >> 6) + (threadIdx.x >> 6);
    if (wave >= NB_USERS) return;

    const int u  = x_users[wave];
    const int xm = x_movies[wave];

    const float nb = fmaxf(1.0f, nbrf[u] - 1.0f);
    const float uf = (rbu[(size_t)u * KDIM + lane] -
                      rbm_saved[(size_t)xm * KDIM + lane]) / nb;
    float p = mf[(size_t)xm * KDIM + lane] * uf;

    #pragma unroll
    for (int off = 32; off > 0; off >>= 1)
        p += __shfl_xor(p, off, 64);

    if (lane == 0)
        out[wave] = (p * (1.0f / 64.0f) * w_out[0] + b_out[0]) * 5.0f;
}

extern "C" void kernel_launch(void* const* d_in, const int* in_sizes, int n_in,
                              void* d_out, int out_size, void* d_ws, size_t ws_size,
                              hipStream_t stream) {
    const int*   x_users      = (const int*)  d_in[0];
    const int*   x_movies     = (const int*)  d_in[1];
    const int*   data_users   = (const int*)  d_in[2];
    const int*   data_movies  = (const int*)  d_in[3];
    const float* data_ratings = (const float*)d_in[4];
    const float* mf           = (const float*)d_in[5];
    const float* W_r          = (const float*)d_in[6];
    const float* b_r          = (const float*)d_in[7];
    const float* W_c          = (const float*)d_in[8];
    const float* b_c          = (const float*)d_in[9];
    const float* w_out        = (const float*)d_in[10];
    const float* b_out        = (const float*)d_in[11];
    float* out = (float*)d_out;

    // workspace layout (~50.8 MB):
    //   rbu       : 6.40M f32 (25.6 MB)   [first 16 MB aliased as `binned` during sort]
    //   nbrf      : 100K f32
    //   rbm_saved : 1.28M f32
    //   sorted_ur : 2M uint2 (16 MB)
    //   mf16      : 1.28M f16 (2.56 MB)
    //   rtab16    : 8193*64 f16 (1.05 MB)
    //   wcfrag    : 4096 f16 (8 KB)
    //   bhist/bstart/bcursor : 3*391 ints
    float*     rbu       = (float*)d_ws;
    uint2*     binned    = (uint2*)d_ws;
    float*     nbrf      = rbu + (size_t)NB_USERS * KDIM;
    float*     rbm_saved = nbrf + NB_USERS;
    uint2*     sorted_ur = (uint2*)(rbm_saved + (size_t)NB_MOVIES * KDIM);
    _Float16*  mf16      = (_Float16*)(sorted_ur + NPTS);
    _Float16*  rtab16    = mf16 + (size_t)NB_MOVIES * KDIM;
    _Float16*  wcfrag    = rtab16 + (size_t)(RQ_LEVELS + 1) * KDIM;
    int*       bhist     = (int*)(wcfrag + 8 * 512);
    int*       bstart    = bhist + NBUCK;
    int*       bcursor   = bstart + NBUCK;

    hipMemsetAsync(bhist, 0, NBUCK * sizeof(int), stream);

    mf16_kernel<<<(NB_MOVIES * KDIM + 255) / 256, 256, 0, stream>>>(mf, mf16);
    rtab16_kernel<<<((RQ_LEVELS + 1) * KDIM + 255) / 256, 256, 0, stream>>>(W_r, b_r, rtab16);
    wcfrag_kernel<<<2, 256, 0, stream>>>(W_c, wcfrag);

    bucket_hist_kernel<<<1024, 256, 0, stream>>>(data_users, bhist);
    bscan_kernel<<<1, 256, 0, stream>>>(bhist, bstart, bcursor);

    binA_kernel<<<NCHUNK, 256, 0, stream>>>(
        data_users, data_movies, data_ratings, bcursor, binned);

    rbm_saved_kernel<<<79, 256, 0, stream>>>(
        data_movies, data_ratings, mf16, rtab16, wcfrag, b_c, rbm_saved);

    binB_kernel<<<NBUCK, 256, 0, stream>>>(binned, bhist, bstart, sorted_ur, nbrf);

    // binned fully consumed -> safe to zero rbu (aliases it)
    hipMemsetAsync(rbu, 0, (size_t)NB_USERS * KDIM * sizeof(float), stream);

    phase1_sorted_kernel<<<2048, 256, 0, stream>>>(
        sorted_ur, mf16, rtab16, wcfrag, b_c, rbu);

    phase2_kernel<<<(NB_USERS * 64 + 255) / 256, 256, 0, stream>>>(
        x_users, x_movies, mf, rbu, nbrf, rbm_saved, w_out, b_out, out);
}

// Round 9
// 196.070 us; speedup vs baseline: 3.5910x; 1.1002x over previous
//
#include <hip/hip_runtime.h>

#define NB_USERS 100000
#define NB_MOVIES 20000
#define KDIM 64
#define NPTS 2000000
#define NTILES (NPTS / 64)
#define RQ_LEVELS 8192            // rating quantization; table rows = RQ_LEVELS+1
#define NBUCK 391                 // ceil(NB_USERS / 256) user buckets (256 users each)
#define CHUNK 4096                // points per binA block
#define NCHUNK ((NPTS + CHUNK - 1) / CHUNK)
#define BCAP 6400                 // pass-B LDS capacity (mean 5115, sigma ~71 -> 18 sigma)
#define LOG2E 1.44269504088896f

typedef _Float16 f16x8 __attribute__((ext_vector_type(8)));
typedef float    f32x4 __attribute__((ext_vector_type(4)));

__device__ __forceinline__ float sigmoidf(float z) {
    return 1.0f / (1.0f + __expf(-z));
}
// w = -log2(e) * z  ->  sigmoid(z) = rcp(1 + 2^w)
__device__ __forceinline__ float sigmoid_w(float w) {
    return __builtin_amdgcn_rcpf(1.0f + __builtin_amdgcn_exp2f(w));
}

// ---------------- prep: f16 tables ----------------

__global__ __launch_bounds__(256) void mf16_kernel(
    const float* __restrict__ mf, _Float16* __restrict__ mf16)
{
    const int idx = blockIdx.x * 256 + threadIdx.x;
    if (idx < NB_MOVIES * KDIM) mf16[idx] = (_Float16)mf[idx];
}

// rtab16[q][k] = sigmoid((q/8192)*W_r[k] + b_r[k]) as f16
__global__ __launch_bounds__(256) void rtab16_kernel(
    const float* __restrict__ W_r, const float* __restrict__ b_r,
    _Float16* __restrict__ rtab16)
{
    const int idx = blockIdx.x * 256 + threadIdx.x;
    const int total = (RQ_LEVELS + 1) * KDIM;
    if (idx >= total) return;
    const int q = idx >> 6, k = idx & 63;
    rtab16[idx] = (_Float16)sigmoidf(fmaf((float)q * (1.0f / RQ_LEVELS), W_r[k], b_r[k]));
}

// W_c^T MFMA B-fragments, f16, PRE-SCALED by -log2(e). layout [ntkt][lane][8].
// fragment: lane l, elem e = W_c[nt*16 + (l&15)][kt*32 + (l>>4)*8 + e]
__global__ __launch_bounds__(256) void wcfrag_kernel(
    const float* __restrict__ W_c, _Float16* __restrict__ wcfrag)
{
    const int idx = blockIdx.x * 256 + threadIdx.x;   // [0, 512)
    if (idx >= 8 * 64) return;
    const int ntkt = idx >> 6;
    const int nt = ntkt >> 1, kt = ntkt & 1;
    const int lane = idx & 63;
    const float* src = &W_c[(nt * 16 + (lane & 15)) * KDIM + kt * 32 + (lane >> 4) * 8];
    _Float16* dst = wcfrag + (size_t)ntkt * 512 + lane * 8;
    #pragma unroll
    for (int e = 0; e < 8; ++e) dst[e] = (_Float16)(src[e] * -LOG2E);
}

// ---------------- bucket histogram (391 coarse buckets) ----------------
__global__ __launch_bounds__(256) void bucket_hist_kernel(
    const int* __restrict__ du, int* __restrict__ bhist)
{
    __shared__ int h[NBUCK];
    for (int b = threadIdx.x; b < NBUCK; b += 256) h[b] = 0;
    __syncthreads();
    int i = blockIdx.x * 256 + threadIdx.x;
    const int stride = gridDim.x * 256;
    for (; i < NPTS; i += stride) atomicAdd(&h[du[i] >> 8], 1);
    __syncthreads();
    for (int b = threadIdx.x; b < NBUCK; b += 256)
        if (h[b]) atomicAdd(&bhist[b], h[b]);
}

// ---------------- bucket scan (1 block) ----------------
__global__ __launch_bounds__(256) void bscan_kernel(
    const int* __restrict__ bhist, int* __restrict__ bstart, int* __restrict__ bcursor)
{
    __shared__ int s[512];
    const int t = threadIdx.x;
    const int v0 = (t < NBUCK) ? bhist[t] : 0;
    const int v1 = (t + 256 < NBUCK) ? bhist[t + 256] : 0;
    s[t] = v0; s[t + 256] = v1;
    __syncthreads();
    for (int d = 1; d < 512; d <<= 1) {
        const int a0 = (t >= d) ? s[t - d] : 0;
        const int a1 = (t + 256 >= d) ? s[t + 256 - d] : 0;
        __syncthreads();
        s[t] += a0; s[t + 256] += a1;
        __syncthreads();
    }
    if (t < NBUCK)       { bstart[t]       = s[t] - v0;       bcursor[t]       = s[t] - v0; }
    if (t + 256 < NBUCK) { bstart[t + 256] = s[t + 256] - v1; bcursor[t + 256] = s[t + 256] - v1; }
}

// ---------------- pass A: bin points by bucket, LDS-grouped writes ----------------
__global__ __launch_bounds__(256) void binA_kernel(
    const int* __restrict__ du, const int* __restrict__ dm,
    const float* __restrict__ dr,
    int* __restrict__ bcursor, uint2* __restrict__ binned)
{
    __shared__ uint2 buf[CHUNK];          // 32 KB
    __shared__ int cnt[NBUCK];
    __shared__ int scn[512];
    __shared__ int sbase[NBUCK];
    __shared__ int cur[NBUCK];
    __shared__ int gbase[NBUCK];

    const int t  = threadIdx.x;
    const int c0 = blockIdx.x * CHUNK;
    const int n  = min(CHUNK, NPTS - c0);

    for (int b = t; b < NBUCK; b += 256) cnt[b] = 0;
    __syncthreads();

    uint2 p[CHUNK / 256];
    #pragma unroll
    for (int j = 0; j < CHUNK / 256; ++j) {
        const int i = c0 + j * 256 + t;
        if (j * 256 + t < n) {
            const unsigned u  = (unsigned)du[i];
            const unsigned m  = (unsigned)dm[i];
            const unsigned rq = (unsigned)(int)fmaf(dr[i], (float)RQ_LEVELS / 5.0f, 0.5f);
            p[j] = make_uint2((u << 15) | m, rq);
            atomicAdd(&cnt[u >> 8], 1);
        } else {
            p[j] = make_uint2(0xFFFFFFFFu, 0u);
        }
    }
    __syncthreads();

    scn[t]       = (t < NBUCK) ? cnt[t] : 0;
    scn[t + 256] = (t + 256 < NBUCK) ? cnt[t + 256] : 0;
    __syncthreads();
    for (int d = 1; d < 512; d <<= 1) {
        const int a0 = (t >= d) ? scn[t - d] : 0;
        const int a1 = (t + 256 >= d) ? scn[t + 256 - d] : 0;
        __syncthreads();
        scn[t] += a0; scn[t + 256] += a1;
        __syncthreads();
    }
    for (int b = t; b < NBUCK; b += 256) {
        const int e = scn[b] - cnt[b];
        sbase[b] = e;
        cur[b]   = e;
        if (cnt[b] > 0) gbase[b] = atomicAdd(&bcursor[b], cnt[b]);
    }
    __syncthreads();

    #pragma unroll
    for (int j = 0; j < CHUNK / 256; ++j) {
        if (p[j].x != 0xFFFFFFFFu) {
            const int b   = p[j].x >> 23;
            const int pos = atomicAdd(&cur[b], 1);
            buf[pos] = p[j];
        }
    }
    __syncthreads();

    for (int i = t; i < n; i += 256) {
        const uint2 q = buf[i];
        const int b = q.x >> 23;
        binned[gbase[b] + (i - sbase[b])] = q;
    }
}

// ---------------- pass B: sort bucket by user in LDS, coalesced write + nbrf ----------------
__global__ __launch_bounds__(256) void binB_kernel(
    const uint2* __restrict__ binned,
    const int* __restrict__ bhist, const int* __restrict__ bstart,
    uint2* __restrict__ sorted, float* __restrict__ nbrf)
{
    __shared__ uint2 buf[BCAP];           // 51.2 KB
    __shared__ int cnt[256];
    __shared__ int cur[256];

    const int t  = threadIdx.x;
    const int b  = blockIdx.x;
    const int n  = bhist[b];
    const int s0 = bstart[b];

    cnt[t] = 0;
    __syncthreads();

    for (int i = t; i < n; i += 256)
        atomicAdd(&cnt[(binned[s0 + i].x >> 15) & 255], 1);
    __syncthreads();

    const int uid = (b << 8) + t;
    if (uid < NB_USERS) nbrf[uid] = (float)cnt[t];

    const int inc = cnt[t];
    cur[t] = inc;
    __syncthreads();
    for (int d = 1; d < 256; d <<= 1) {
        const int a = (t >= d) ? cur[t - d] : 0;
        __syncthreads();
        cur[t] += a;
        __syncthreads();
    }
    const int excl = cur[t] - inc;
    __syncthreads();
    cur[t] = excl;
    __syncthreads();

    for (int i = t; i < n; i += 256) {
        const uint2 q  = binned[s0 + i];
        const int  lu  = (q.x >> 15) & 255;
        const int  pos = atomicAdd(&cur[lu], 1);
        buf[pos] = q;
    }
    __syncthreads();

    for (int i = t; i < n; i += 256)
        sorted[s0 + i] = buf[i];
}

// ---------------- rbm_saved: rows n < 20000 from the UNSORTED stream (f16 path) ----------------
__global__ __launch_bounds__(256) void rbm_saved_kernel(
    const int* __restrict__ dm, const float* __restrict__ dr,
    const _Float16* __restrict__ mf16, const _Float16* __restrict__ rtab16,
    const _Float16* __restrict__ wcfrag, const float* __restrict__ b_c,
    float* __restrict__ rbm_saved)
{
    __shared__ _Float16 bsh[8 * 512];     // 8 KB: W_c fragments (pre-scaled by -log2e)
    for (int i = threadIdx.x; i < 512; i += 256)
        ((f16x8*)bsh)[i] = ((const f16x8*)wcfrag)[i];
    __syncthreads();

    const int lane = threadIdx.x & 63;
    const int wave = blockIdx.x * (blockDim.x >> 6) + (threadIdx.x >> 6);
    const int NT = (NB_MOVIES + 63) / 64;      // 313
    if (wave >= NT) return;

    float wbcv[4];
    #pragma unroll
    for (int nt = 0; nt < 4; ++nt) wbcv[nt] = -LOG2E * b_c[nt * 16 + (lane & 15)];

    const int base = wave * 64;
    const int koff = (lane >> 4) * 8;

    #pragma unroll 1
    for (int mt = 0; mt < 4; ++mt) {
        const int pg = base + mt * 16 + (lane & 15);
        int   m = 0;
        float r = 0.f;
        if (pg < NB_MOVIES) { m = dm[pg]; r = dr[pg]; }
        const int rq = (int)fmaf(r, (float)RQ_LEVELS / 5.0f, 0.5f);

        const f16x8 ma = *(const f16x8*)(mf16   + (size_t)m  * KDIM + koff);
        const f16x8 mb = *(const f16x8*)(mf16   + (size_t)m  * KDIM + 32 + koff);
        const f16x8 ta = *(const f16x8*)(rtab16 + (size_t)rq * KDIM + koff);
        const f16x8 tb = *(const f16x8*)(rtab16 + (size_t)rq * KDIM + 32 + koff);
        const f16x8 a0 = ma * ta;
        const f16x8 a1 = mb * tb;

        f32x4 acc[4];
        #pragma unroll
        for (int nt = 0; nt < 4; ++nt) {
            const f16x8 b0 = *(const f16x8*)(bsh + (nt * 2 + 0) * 512 + lane * 8);
            const f16x8 b1 = *(const f16x8*)(bsh + (nt * 2 + 1) * 512 + lane * 8);
            acc[nt] = (f32x4){0.f, 0.f, 0.f, 0.f};
            acc[nt] = __builtin_amdgcn_mfma_f32_16x16x32_f16(a0, b0, acc[nt], 0, 0, 0);
            acc[nt] = __builtin_amdgcn_mfma_f32_16x16x32_f16(a1, b1, acc[nt], 0, 0, 0);
        }

        #pragma unroll
        for (int reg = 0; reg < 4; ++reg) {
            const int prow_g = base + mt * 16 + (lane >> 4) * 4 + reg;
            if (prow_g < NB_MOVIES) {
                #pragma unroll
                for (int nt = 0; nt < 4; ++nt) {
                    const float rbm = sigmoid_w(acc[nt][reg] + wbcv[nt]);
                    rbm_saved[(size_t)prow_g * KDIM + nt * 16 + (lane & 15)] = rbm;
                }
            }
        }
    }
}

// ---------------- phase 1: user-sorted stream, f16 fragment-direct, segmented reduce ----------------
__global__ __launch_bounds__(256, 4) void phase1_sorted_kernel(
    const uint2* __restrict__ sorted_ur,
    const _Float16* __restrict__ mf16,
    const _Float16* __restrict__ rtab16,
    const _Float16* __restrict__ wcfrag,
    const float* __restrict__ b_c,
    float* __restrict__ rbu)
{
    __shared__ _Float16 bsh[8 * 512];     // 8 KB: W_c fragments [ntkt][lane][8], pre-scaled
    for (int i = threadIdx.x; i < 512; i += 256)
        ((f16x8*)bsh)[i] = ((const f16x8*)wcfrag)[i];
    __syncthreads();

    const int lane = threadIdx.x & 63;
    const int wave = blockIdx.x * (blockDim.x >> 6) + (threadIdx.x >> 6);
    const int nwav = gridDim.x * (blockDim.x >> 6);

    float wbcv[4];
    #pragma unroll
    for (int nt = 0; nt < 4; ++nt) wbcv[nt] = -LOG2E * b_c[nt * 16 + (lane & 15)];

    const int koff = (lane >> 4) * 8;
    const int g    = lane >> 4;

    for (int it = wave; it < NTILES; it += nwav) {
        const int base = it * 64;

        #pragma unroll 1
        for (int mt = 0; mt < 4; ++mt) {
            const uint2 ur = sorted_ur[base + mt * 16 + (lane & 15)];
            const unsigned u_at = ur.x >> 15;
            const int      m    = (int)(ur.x & 0x7fffu);
            const int      rq   = (int)ur.y;

            const f16x8 ma = *(const f16x8*)(mf16   + (size_t)m  * KDIM + koff);
            const f16x8 mb = *(const f16x8*)(mf16   + (size_t)m  * KDIM + 32 + koff);
            const f16x8 ta = *(const f16x8*)(rtab16 + (size_t)rq * KDIM + koff);
            const f16x8 tb = *(const f16x8*)(rtab16 + (size_t)rq * KDIM + 32 + koff);
            const f16x8 a0 = ma * ta;     // v_pk_mul_f16
            const f16x8 a1 = mb * tb;

            f32x4 acc[4];
            #pragma unroll
            for (int nt = 0; nt < 4; ++nt) {
                const f16x8 b0 = *(const f16x8*)(bsh + (nt * 2 + 0) * 512 + lane * 8);
                const f16x8 b1 = *(const f16x8*)(bsh + (nt * 2 + 1) * 512 + lane * 8);
                acc[nt] = (f32x4){0.f, 0.f, 0.f, 0.f};
                acc[nt] = __builtin_amdgcn_mfma_f32_16x16x32_f16(a0, b0, acc[nt], 0, 0, 0);
                acc[nt] = __builtin_amdgcn_mfma_f32_16x16x32_f16(a1, b1, acc[nt], 0, 0, 0);
            }

            // sigmoid in place: acc[nt][reg] = rbm for point (g*4+reg), feat nt*16+(lane&15)
            #pragma unroll
            for (int nt = 0; nt < 4; ++nt)
                #pragma unroll
                for (int reg = 0; reg < 4; ++reg)
                    acc[nt][reg] = sigmoid_w(acc[nt][reg] + wbcv[nt]);

            const unsigned u_prev =
                (unsigned)__shfl((int)u_at, lane - 1, 64);
            const bool boundary = ((lane & 15) == 0) || (u_at != u_prev);
            unsigned long long bm = __ballot(boundary) & 0xFFFFull;

            while (bm) {
                const int s = __builtin_ctzll(bm);
                bm &= bm - 1;
                const int e = bm ? __builtin_ctzll(bm) : 16;
                const unsigned useg =
                    (unsigned)__builtin_amdgcn_readlane((int)u_at, s);

                const int lo = s - g * 4;
                const int hi = e - g * 4;
                float p0 = 0.f, p1 = 0.f, p2 = 0.f, p3 = 0.f;
                #pragma unroll
                for (int reg = 0; reg < 4; ++reg) {
                    const bool in = (reg >= lo) && (reg < hi);
                    p0 += in ? acc[0][reg] : 0.f;
                    p1 += in ? acc[1][reg] : 0.f;
                    p2 += in ? acc[2][reg] : 0.f;
                    p3 += in ? acc[3][reg] : 0.f;
                }
                p0 += __shfl_xor(p0, 16, 64); p0 += __shfl_xor(p0, 32, 64);
                p1 += __shfl_xor(p1, 16, 64); p1 += __shfl_xor(p1, 32, 64);
                p2 += __shfl_xor(p2, 16, 64); p2 += __shfl_xor(p2, 32, 64);
                p3 += __shfl_xor(p3, 16, 64); p3 += __shfl_xor(p3, 32, 64);

                const float v01 = (g & 1) ? p1 : p0;
                const float v23 = (g & 1) ? p3 : p2;
                const float val = (g & 2) ? v23 : v01;
                atomicAdd(&rbu[(size_t)useg * KDIM + lane], val);
            }
        }
    }
}

// ---------------- phase 2 ----------------
__global__ __launch_bounds__(256) void phase2_kernel(
    const int* __restrict__ x_users,
    const int* __restrict__ x_movies,
    const float* __restrict__ mf,
    const float* __restrict__ rbu,
    const float* __restrict__ nbrf,
    const float* __restrict__ rbm_saved,
    const float* __restrict__ w_out,
    const float* __restrict__ b_out,
    float* __restrict__ out)
{
    const int lane = threadIdx.x & 63;
    const int wave = blockIdx.x * (blockDim.x >> 6) + (threadIdx.x >> 6);
    if (wave >= NB_USERS) return;

    const int u  = x_users[wave];
    const int xm = x_movies[wave];

    const float nb = fmaxf(1.0f, nbrf[u] - 1.0f);
    const float uf = (rbu[(size_t)u * KDIM + lane] -
                      rbm_saved[(size_t)xm * KDIM + lane]) / nb;
    float p = mf[(size_t)xm * KDIM + lane] * uf;

    #pragma unroll
    for (int off = 32; off > 0; off >>= 1)
        p += __shfl_xor(p, off, 64);

    if (lane == 0)
        out[wave] = (p * (1.0f / 64.0f) * w_out[0] + b_out[0]) * 5.0f;
}

extern "C" void kernel_launch(void* const* d_in, const int* in_sizes, int n_in,
                              void* d_out, int out_size, void* d_ws, size_t ws_size,
                              hipStream_t stream) {
    const int*   x_users      = (const int*)  d_in[0];
    const int*   x_movies     = (const int*)  d_in[1];
    const int*   data_users   = (const int*)  d_in[2];
    const int*   data_movies  = (const int*)  d_in[3];
    const float* data_ratings = (const float*)d_in[4];
    const float* mf           = (const float*)d_in[5];
    const float* W_r          = (const float*)d_in[6];
    const float* b_r          = (const float*)d_in[7];
    const float* W_c          = (const float*)d_in[8];
    const float* b_c          = (const float*)d_in[9];
    const float* w_out        = (const float*)d_in[10];
    const float* b_out        = (const float*)d_in[11];
    float* out = (float*)d_out;

    // workspace layout (~50.8 MB):
    //   rbu       : 6.40M f32 (25.6 MB)   [first 16 MB aliased as `binned` during sort]
    //   nbrf      : 100K f32
    //   rbm_saved : 1.28M f32
    //   sorted_ur : 2M uint2 (16 MB)
    //   mf16      : 1.28M f16 (2.56 MB)
    //   rtab16    : 8193*64 f16 (1.05 MB)
    //   wcfrag    : 4096 f16 (8 KB)
    //   bhist/bstart/bcursor : 3*391 ints
    float*     rbu       = (float*)d_ws;
    uint2*     binned    = (uint2*)d_ws;
    float*     nbrf      = rbu + (size_t)NB_USERS * KDIM;
    float*     rbm_saved = nbrf + NB_USERS;
    uint2*     sorted_ur = (uint2*)(rbm_saved + (size_t)NB_MOVIES * KDIM);
    _Float16*  mf16      = (_Float16*)(sorted_ur + NPTS);
    _Float16*  rtab16    = mf16 + (size_t)NB_MOVIES * KDIM;
    _Float16*  wcfrag    = rtab16 + (size_t)(RQ_LEVELS + 1) * KDIM;
    int*       bhist     = (int*)(wcfrag + 8 * 512);
    int*       bstart    = bhist + NBUCK;
    int*       bcursor   = bstart + NBUCK;

    hipMemsetAsync(bhist, 0, NBUCK * sizeof(int), stream);

    mf16_kernel<<<(NB_MOVIES * KDIM + 255) / 256, 256, 0, stream>>>(mf, mf16);
    rtab16_kernel<<<((RQ_LEVELS + 1) * KDIM + 255) / 256, 256, 0, stream>>>(W_r, b_r, rtab16);
    wcfrag_kernel<<<2, 256, 0, stream>>>(W_c, wcfrag);

    bucket_hist_kernel<<<1024, 256, 0, stream>>>(data_users, bhist);
    bscan_kernel<<<1, 256, 0, stream>>>(bhist, bstart, bcursor);

    binA_kernel<<<NCHUNK, 256, 0, stream>>>(
        data_users, data_movies, data_ratings, bcursor, binned);

    rbm_saved_kernel<<<79, 256, 0, stream>>>(
        data_movies, data_ratings, mf16, rtab16, wcfrag, b_c, rbm_saved);

    binB_kernel<<<NBUCK, 256, 0, stream>>>(binned, bhist, bstart, sorted_ur, nbrf);

    // binned fully consumed -> safe to zero rbu (aliases it)
    hipMemsetAsync(rbu, 0, (size_t)NB_USERS * KDIM * sizeof(float), stream);

    phase1_sorted_kernel<<<2048, 256, 0, stream>>>(
        sorted_ur, mf16, rtab16, wcfrag, b_c, rbu);

    phase2_kernel<<<(NB_USERS * 64 + 255) / 256, 256, 0, stream>>>(
        x_users, x_movies, mf, rbu, nbrf, rbm_saved, w_out, b_out, out);
}